// Round 4
// baseline (1032.985 us; speedup 1.0000x reference)
//
#include <hip/hip_runtime.h>
#include <hip/hip_bf16.h>

// ---------------- sizes ----------------
// B=8, C=64, H=W=96, S=9216, NH=4 (dil=1,2,4,8), NL=8, hid=16
// KV rows per (i,b): 256 (0..127 = K via k_w, 128..255 = V via v_w)
// conv GEMM per (i,b): [256 o] x [576 k = tap*64+c] x [9216 s], bf16 MFMA

// ---------------- workspace layout (bytes) ----------------
#define WS_CENPAD 0UL           // bf16 [8][64][112][112]     = 12,845,056
#define WS_W      25690112UL    // bf16 [4][18][256][32]      =  1,179,648 (frag-ready)
#define WS_Q      28049408UL    // bf16 [8][64][9216]         =  9,437,184 (row = o*4+i)
#define WS_KV     46923776UL    // bf16 [4][8][256][9216]     = 150,994,944
#define WS_SPART  197918720UL   // f32 [288][2048]            =  2,359,296
#define WS_KKP    200278016UL   // f32 [288][128]             =    147,456
#define WS_QQP    200425472UL   // f32 [288][16]              =     18,432
#define WS_ATTN   200443904UL   // f32 [32][128][16]          =    262,144
#define WS_OUT    200706048UL   // f32 [8][64][9216]          = 18,874,368
#define WS_BN     219580416UL   // f32 [128] (atomic sums: [0..63]=sum, [64..127]=sumsq)

typedef __attribute__((ext_vector_type(8))) short short8;
typedef __attribute__((ext_vector_type(4))) float f32x4;

__device__ __forceinline__ float bflo(unsigned int u){ return __uint_as_float(u<<16); }
__device__ __forceinline__ float bfhi(unsigned int u){ return __uint_as_float(u & 0xffff0000u); }
__device__ __forceinline__ unsigned short f2bf(float f){
  unsigned int u = __float_as_uint(f);
  return (unsigned short)((u + 0x7fffu + ((u>>16)&1u)) >> 16);
}
__device__ __forceinline__ unsigned short fbits(float f){
  __hip_bfloat16 h = __float2bfloat16(f);
  return __builtin_bit_cast(unsigned short, h);
}

// ---- pad: cen [8,64,96,96] f32 -> cenbf [8,64,112,112] bf16 (8-halo zeros)
__global__ __launch_bounds__(256) void pad_kernel(const float* __restrict__ cen, unsigned short* __restrict__ cenbf){
  int idx = blockIdx.x*256 + threadIdx.x;  // exactly 6,422,528 threads
  int px = idx % 112; int t = idx / 112; int py = t % 112; int bc = t / 112;
  int y = py - 8, x = px - 8;
  float v = 0.f;
  if (y >= 0 && y < 96 && x >= 0 && x < 96) v = cen[(size_t)bc*9216 + y*96 + x];
  cenbf[idx] = fbits(v);
}

// ---- prep: build conv weights in bf16, fragment-ready layout
// Wb[((i*18 + kc)*256 + o)*32 + k'] where k = t*64 + c, kc=k>>5, k'=k&31
__global__ __launch_bounds__(256) void prep_kernel(const float* __restrict__ sumw,
    const float* __restrict__ kw, const float* __restrict__ vw, unsigned short* __restrict__ Wb){
  int idx = blockIdx.x*256 + threadIdx.x;  // exactly 589,824
  int o = idx & 255; int r = idx >> 8; int c = r & 63; r >>= 6; int t = r % 9; int i = r / 9;
  float l0 = sumw[(i*64 + c)*2 + 0], l1 = sumw[(i*64 + c)*2 + 1];
  float m = fmaxf(l0, l1);
  float e0 = expf(l0 - m), e1 = expf(l1 - m);
  float inv = 1.f/(e0 + e1);
  float sw0 = e0*inv, sw1 = e1*inv;
  const float* wsrc = (o < 128) ? (kw + ((size_t)i*128 + o)*512 + c)
                                : (vw + ((size_t)i*128 + (o-128))*512 + c);
  float A = 0.f;
  #pragma unroll
  for (int j = 0; j < 8; ++j) A += wsrc[j*64];
  float val;
  if (t == 4) {
    val = A;  // center tap: all mixed kernels have weight 1 at center (sw0+sw1=1)
  } else {
    const int tmap[9] = {0,1,2,7,0,3,6,5,4};
    int j = tmap[t];
    val = -(wsrc[j*64]*sw0 + A*sw1*0.125f);
  }
  int k = t*64 + c;
  Wb[(((size_t)i*18 + (k>>5))*256 + o)*32 + (k&31)] = f2bf(val);
}

// ---- Q projection: read cen ONCE, compute all 4 shifts x 16 rows -> Q bf16
// qbf[b][row][s], row = o*4 + i  (global q-row order from the stack/reshape)
__global__ __launch_bounds__(256) void qproj_kernel(const float* __restrict__ cen,
    const float* __restrict__ qw, unsigned short* __restrict__ qbf){
  __shared__ float WT[64][64];  // [c][row]
  int tid = threadIdx.x;
  int st = blockIdx.x, b = blockIdx.y;
  #pragma unroll
  for (int e = 0; e < 16; ++e) {
    int f = e*256 + tid; int c = f >> 6, row = f & 63;
    int i = row & 3, o = row >> 2;
    WT[c][row] = qw[(size_t)i*1024 + o*64 + c];
  }
  __syncthreads();
  int s = st*256 + tid;
  float acc[64];
  #pragma unroll
  for (int r = 0; r < 64; ++r) acc[r] = 0.f;
  const float* cb = cen + (size_t)b*64*9216 + s;
  for (int c = 0; c < 64; ++c) {
    float xv = cb[(size_t)c*9216];
    #pragma unroll
    for (int r4 = 0; r4 < 16; ++r4) {
      float4 w = *(const float4*)&WT[c][r4*4];
      acc[r4*4+0] = fmaf(w.x, xv, acc[r4*4+0]);
      acc[r4*4+1] = fmaf(w.y, xv, acc[r4*4+1]);
      acc[r4*4+2] = fmaf(w.z, xv, acc[r4*4+2]);
      acc[r4*4+3] = fmaf(w.w, xv, acc[r4*4+3]);
    }
  }
  unsigned short* qb = qbf + (size_t)b*64*9216 + s;
  #pragma unroll
  for (int r = 0; r < 64; ++r) qb[(size_t)r*9216] = fbits(acc[r]);
}

// ---- conv K/V via MFMA: per (i,b) GEMM [256 o] x [576 k] x [9216 s] -> bf16 KV
// 512 thr = 8 waves (2 wm x 4 wn); tile O=256 x S=256; K chunks of 32
// Raw s_barrier (lgkm-only drain) so gather prefetch stays in flight across
// barriers (counted-vmcnt pipeline, T4). Double-buffered LDS.
__global__ __launch_bounds__(512, 2) void conv_kv_mfma(const unsigned short* __restrict__ cenbf,
    const unsigned short* __restrict__ Wb, unsigned short* __restrict__ KV){
  __shared__ char Xs[2][256*72];
  const int tid = threadIdx.x;
  const int st = blockIdx.x, ib = blockIdx.z;
  const int i = ib >> 3, b = ib & 7;
  const int dil = 1 << i;
  const int s0 = st*256;
  const int wave = tid >> 6, lane = tid & 63;
  const int wm = wave >> 2, wn = wave & 3;
  const int l15 = lane & 15, l4 = lane >> 4;
  // staging mapping: thread covers (s_idx, k' = khalf*16 .. +15)
  const int s_idx = tid & 255;
  const int khalf = tid >> 8;
  const int s = s0 + s_idx;
  const int y = s / 96, x = s - y*96;
  const unsigned short* cb = cenbf + (size_t)b*802816 + (size_t)(y+8)*112 + (x+8);

  f32x4 acc[8][4];
  #pragma unroll
  for (int mf = 0; mf < 8; ++mf)
    #pragma unroll
    for (int nf = 0; nf < 4; ++nf)
      acc[mf][nf] = (f32x4){0.f, 0.f, 0.f, 0.f};

  const unsigned short* Wi = Wb + (size_t)i*18*8192;

  unsigned short vs[16];
  auto gather = [&](int kn){
    int t = kn >> 1;
    int cbase = (kn & 1)*32 + khalf*16;
    int dy = (t/3 - 1)*dil, dx = (t - (t/3)*3 - 1)*dil;
    const unsigned short* p = cb + (size_t)cbase*12544 + (dy*112 + dx);
    #pragma unroll
    for (int j = 0; j < 16; ++j) vs[j] = p[(size_t)j*12544];
  };

  gather(0);   // prologue
  int buf = 0;
  for (int kc = 0; kc < 18; ++kc) {
    // ---- 1. pack chunk-kc gather & write LDS buf (compiler emits counted
    //         vmcnt wait for the gather here)
    char* wp = Xs[buf] + s_idx*72 + khalf*32;
    #pragma unroll
    for (int w = 0; w < 4; ++w) {
      unsigned int p0 = (unsigned int)vs[4*w+0] | ((unsigned int)vs[4*w+1] << 16);
      unsigned int p1 = (unsigned int)vs[4*w+2] | ((unsigned int)vs[4*w+3] << 16);
      *(uint2*)(wp + w*8) = make_uint2(p0, p1);
    }
    // ---- 2. LDS-only drain + raw barrier (NO vmcnt drain — the whole point)
    asm volatile("s_waitcnt lgkmcnt(0)" ::: "memory");
    __builtin_amdgcn_s_barrier();
    asm volatile("" ::: "memory");
    // ---- 3. A fragments (issued BEFORE next gather so the MFMA A-wait is
    //         vmcnt(16), leaving the gather in flight)
    short8 a[8];
    const unsigned short* ap = Wi + (size_t)kc*8192 + (size_t)(wm*128 + l15)*32 + l4*8;
    #pragma unroll
    for (int mf = 0; mf < 8; ++mf) a[mf] = *(const short8*)(ap + mf*512);
    asm volatile("" ::: "memory");   // pin A-loads before gather issue
    // ---- 4. prefetch next chunk's gather (hidden under this chunk's MFMA)
    if (kc < 17) gather(kc + 1);
    // ---- 5. B fragments from LDS (72B rows -> conflict-free)
    short8 bfr[4];
    #pragma unroll
    for (int nf = 0; nf < 4; ++nf) {
      const char* rp = Xs[buf] + (wn*64 + nf*16 + l15)*72 + l4*16;
      uint2 lo = *(const uint2*)rp;
      uint2 hi = *(const uint2*)(rp + 8);
      uint4 tb = make_uint4(lo.x, lo.y, hi.x, hi.y);
      bfr[nf] = *(short8*)&tb;
    }
    // ---- 6. MFMA
    #pragma unroll
    for (int mf = 0; mf < 8; ++mf)
      #pragma unroll
      for (int nf = 0; nf < 4; ++nf)
        acc[mf][nf] = __builtin_amdgcn_mfma_f32_16x16x32_bf16(a[mf], bfr[nf], acc[mf][nf], 0, 0, 0);
    buf ^= 1;
  }

  // ---- epilogue: C/D mapping row=(l>>4)*4+r, col=l&15
  #pragma unroll
  for (int mf = 0; mf < 8; ++mf) {
    #pragma unroll
    for (int nf = 0; nf < 4; ++nf) {
      int scol = s0 + wn*64 + nf*16 + l15;
      int obase = wm*128 + mf*16 + l4*4;
      #pragma unroll
      for (int r = 0; r < 4; ++r)
        KV[((size_t)ib*256 + obase + r)*9216 + scol] = fbits(acc[mf][nf][r]);
    }
  }
}

// ---- scores: per (b,hh,chunk of 1024 s): partial 16x128 dots + row sumsq
__global__ __launch_bounds__(256) void scores_kernel(const unsigned short* __restrict__ KV,
    const unsigned short* __restrict__ qbf, float* __restrict__ spart,
    float* __restrict__ kkpart, float* __restrict__ qqpart){
  __shared__ float Klds[64][128];  // [s][kr]
  __shared__ float Qlds[16][64];   // [qr][s]
  const int tid = threadIdx.x;
  const int chunk = blockIdx.x, hh = blockIdx.y, b = blockIdx.z;
  const int kr = tid & 127, qrg = (tid >> 7) * 8;
  float acc[8] = {0,0,0,0,0,0,0,0};
  float kacc = 0.f, qacc = 0.f;
  const int skr = tid >> 2;
  const int sq16 = (tid & 3) * 16;
  const int qrow = tid >> 4, qoff = (tid & 15) * 4;
  const unsigned short* qsrc = qbf + ((size_t)(b*64 + hh*16 + qrow))*9216;

  for (int sc = 0; sc < 16; ++sc) {
    int sb = chunk*1024 + sc*64;
    #pragma unroll
    for (int p = 0; p < 2; ++p) {
      int krr = p*64 + skr;
      int ii = krr & 3, oo = hh*32 + (krr >> 2);
      const unsigned short* src = KV + ((size_t)((ii*8 + b)*256 + oo))*9216 + sb + sq16;
      uint4 u0 = *(const uint4*)src;
      uint4 u1 = *(const uint4*)(src + 8);
      Klds[sq16+ 0][krr] = bflo(u0.x); Klds[sq16+ 1][krr] = bfhi(u0.x);
      Klds[sq16+ 2][krr] = bflo(u0.y); Klds[sq16+ 3][krr] = bfhi(u0.y);
      Klds[sq16+ 4][krr] = bflo(u0.z); Klds[sq16+ 5][krr] = bfhi(u0.z);
      Klds[sq16+ 6][krr] = bflo(u0.w); Klds[sq16+ 7][krr] = bfhi(u0.w);
      Klds[sq16+ 8][krr] = bflo(u1.x); Klds[sq16+ 9][krr] = bfhi(u1.x);
      Klds[sq16+10][krr] = bflo(u1.y); Klds[sq16+11][krr] = bfhi(u1.y);
      Klds[sq16+12][krr] = bflo(u1.z); Klds[sq16+13][krr] = bfhi(u1.z);
      Klds[sq16+14][krr] = bflo(u1.w); Klds[sq16+15][krr] = bfhi(u1.w);
    }
    {
      uint2 uq = *(const uint2*)(qsrc + sb + qoff);
      float4 qv = make_float4(bflo(uq.x), bfhi(uq.x), bflo(uq.y), bfhi(uq.y));
      *(float4*)&Qlds[qrow][qoff] = qv;
    }
    __syncthreads();
    #pragma unroll 4
    for (int s4 = 0; s4 < 16; ++s4) {
      float k0 = Klds[s4*4+0][kr], k1 = Klds[s4*4+1][kr];
      float k2 = Klds[s4*4+2][kr], k3 = Klds[s4*4+3][kr];
      if (tid < 128) kacc += k0*k0 + k1*k1 + k2*k2 + k3*k3;
      #pragma unroll
      for (int q = 0; q < 8; ++q) {
        float4 qv = *(const float4*)&Qlds[qrg + q][s4*4];
        acc[q] += k0*qv.x + k1*qv.y + k2*qv.z + k3*qv.w;
      }
      if (tid >= 128 && tid < 144) {
        float4 qv = *(const float4*)&Qlds[tid & 15][s4*4];
        qacc += qv.x*qv.x + qv.y*qv.y + qv.z*qv.z + qv.w*qv.w;
      }
    }
    __syncthreads();
  }
  int pb = (b*4 + hh)*9 + chunk;
  #pragma unroll
  for (int q = 0; q < 8; ++q) spart[(size_t)pb*2048 + (qrg+q)*128 + kr] = acc[q];
  if (tid < 128) kkpart[(size_t)pb*128 + tid] = kacc;
  if (tid >= 128 && tid < 144) qqpart[(size_t)pb*16 + (tid - 128)] = qacc;
}

// ---- softmax: reduce partials, l2-normalize scale, instance-norm, row softmax -> attnT[kr][qr]
__global__ __launch_bounds__(256) void softmax_kernel(const float* __restrict__ spart,
    const float* __restrict__ kkpart, const float* __restrict__ qqpart, float* __restrict__ attnT){
  const int pb = blockIdx.x, tid = threadIdx.x;
  const int qr = tid >> 4, g = tid & 15;
  __shared__ float kkl[128];
  __shared__ float qql[16];
  __shared__ float red[8];
  __shared__ float stats[2];
  float sv[8] = {0,0,0,0,0,0,0,0};
  for (int ch = 0; ch < 9; ++ch) {
    const float* p = spart + ((size_t)(pb*9 + ch))*2048 + qr*128 + g*8;
    #pragma unroll
    for (int e = 0; e < 8; ++e) sv[e] += p[e];
  }
  if (tid < 128) { float ssum = 0.f; for (int ch = 0; ch < 9; ++ch) ssum += kkpart[(size_t)(pb*9+ch)*128 + tid]; kkl[tid] = ssum; }
  if (tid < 16)  { float ssum = 0.f; for (int ch = 0; ch < 9; ++ch) ssum += qqpart[(size_t)(pb*9+ch)*16 + tid]; qql[tid] = ssum; }
  __syncthreads();
  float qn = fmaxf(sqrtf(qql[qr]), 1e-12f);
  float lsum = 0.f, lsq = 0.f;
  #pragma unroll
  for (int e = 0; e < 8; ++e) {
    float kn = fmaxf(sqrtf(kkl[g*8+e]), 1e-12f);
    float v = sv[e] / (qn * kn * 96.0f);
    sv[e] = v; lsum += v; lsq += v*v;
  }
  #pragma unroll
  for (int m = 1; m <= 32; m <<= 1) { lsum += __shfl_xor(lsum, m); lsq += __shfl_xor(lsq, m); }
  if ((tid & 63) == 0) { red[tid >> 6] = lsum; red[4 + (tid >> 6)] = lsq; }
  __syncthreads();
  if (tid == 0) {
    float ts = red[0]+red[1]+red[2]+red[3];
    float tq = red[4]+red[5]+red[6]+red[7];
    float mean = ts / 2048.0f;
    float var = tq / 2048.0f - mean*mean;
    stats[0] = mean; stats[1] = rsqrtf(var + 1e-5f);
  }
  __syncthreads();
  float mean = stats[0], inv = stats[1];
  float mx = -1e30f;
  #pragma unroll
  for (int e = 0; e < 8; ++e) { sv[e] = (sv[e] - mean) * inv; mx = fmaxf(mx, sv[e]); }
  #pragma unroll
  for (int m = 1; m <= 8; m <<= 1) mx = fmaxf(mx, __shfl_xor(mx, m));
  float es = 0.f;
  #pragma unroll
  for (int e = 0; e < 8; ++e) { sv[e] = expf(sv[e] - mx); es += sv[e]; }
  #pragma unroll
  for (int m = 1; m <= 8; m <<= 1) es += __shfl_xor(es, m);
  float rinv = 1.0f / es;
  #pragma unroll
  for (int e = 0; e < 8; ++e) attnT[(size_t)pb*2048 + (g*8+e)*16 + qr] = sv[e] * rinv;
}

// ---- PV: out[b][hh*16+qr][s] = sum_kr attn * V
__global__ __launch_bounds__(256) void pv_kernel(const unsigned short* __restrict__ KV,
    const float* __restrict__ attnT, float* __restrict__ outbuf){
  __shared__ float at[128][16];
  int tid = threadIdx.x;
  int st = blockIdx.x, hh = blockIdx.y, b = blockIdx.z;
  const float* ap = attnT + ((size_t)(b*4 + hh))*2048;
  #pragma unroll
  for (int e = 0; e < 8; ++e) ((float*)at)[e*256 + tid] = ap[e*256 + tid];
  __syncthreads();
  int sbase = st*1024 + tid*4;
  float acc[16][4];
  #pragma unroll
  for (int q = 0; q < 16; ++q)
    #pragma unroll
    for (int p = 0; p < 4; ++p) acc[q][p] = 0.f;
  #pragma unroll 2
  for (int kr = 0; kr < 128; ++kr) {
    int ii = kr & 3, oo = 128 + hh*32 + (kr >> 2);
    const unsigned short* vp = KV + ((size_t)((ii*8 + b)*256 + oo))*9216 + sbase;
    uint2 u = *(const uint2*)vp;
    float v0 = bflo(u.x), v1 = bfhi(u.x), v2 = bflo(u.y), v3 = bfhi(u.y);
    #pragma unroll
    for (int q4 = 0; q4 < 4; ++q4) {
      float4 a = *(const float4*)&at[kr][q4*4];
      float av[4] = {a.x, a.y, a.z, a.w};
      #pragma unroll
      for (int j = 0; j < 4; ++j) {
        acc[q4*4+j][0] = fmaf(av[j], v0, acc[q4*4+j][0]);
        acc[q4*4+j][1] = fmaf(av[j], v1, acc[q4*4+j][1]);
        acc[q4*4+j][2] = fmaf(av[j], v2, acc[q4*4+j][2]);
        acc[q4*4+j][3] = fmaf(av[j], v3, acc[q4*4+j][3]);
      }
    }
  }
  float* ob = outbuf + ((size_t)(b*64 + hh*16))*9216 + sbase;
  #pragma unroll
  for (int q = 0; q < 16; ++q) {
    float4 w = make_float4(acc[q][0], acc[q][1], acc[q][2], acc[q][3]);
    *(float4*)(ob + (size_t)q*9216) = w;
  }
}

// ---- 1x1 out conv -> d_out (pre-BN) + fused BN partial sums (atomics)
__global__ __launch_bounds__(256) void outconv_kernel(const float* __restrict__ outbuf,
    const float* __restrict__ ow, float* __restrict__ dout, float* __restrict__ bnacc){
  __shared__ float WT[64][64];  // [c][o]
  int tid = threadIdx.x; int st = blockIdx.x; int b = blockIdx.y;
  #pragma unroll
  for (int e = 0; e < 16; ++e) {
    int f = e*256 + tid; int c = f >> 6, o = f & 63;
    WT[c][o] = ow[o*64 + c];
  }
  __syncthreads();
  int s = st*256 + tid;
  float acc[64];
  #pragma unroll
  for (int o = 0; o < 64; ++o) acc[o] = 0.f;
  for (int c = 0; c < 64; ++c) {
    float xv = outbuf[((size_t)(b*64 + c))*9216 + s];
    #pragma unroll
    for (int o4 = 0; o4 < 16; ++o4) {
      float4 w = *(const float4*)&WT[c][o4*4];
      acc[o4*4+0] = fmaf(w.x, xv, acc[o4*4+0]);
      acc[o4*4+1] = fmaf(w.y, xv, acc[o4*4+1]);
      acc[o4*4+2] = fmaf(w.z, xv, acc[o4*4+2]);
      acc[o4*4+3] = fmaf(w.w, xv, acc[o4*4+3]);
    }
  }
  #pragma unroll
  for (int o = 0; o < 64; ++o) dout[((size_t)(b*64 + o))*9216 + s] = acc[o];
  // fused BN partials: 64-lane butterfly per channel, one atomic per wave
  int lane = tid & 63;
  #pragma unroll
  for (int o = 0; o < 64; ++o) {
    float sv = acc[o], sq = acc[o]*acc[o];
    #pragma unroll
    for (int m = 1; m <= 32; m <<= 1) { sv += __shfl_xor(sv, m); sq += __shfl_xor(sq, m); }
    if (lane == 0) { atomicAdd(bnacc + o, sv); atomicAdd(bnacc + 64 + o, sq); }
  }
}

// ---- BN apply + ReLU (in place on d_out), float4; finalizes stats from sums
__global__ __launch_bounds__(256) void bnapply_kernel(float* __restrict__ yb,
    const float* __restrict__ bn, const float* __restrict__ gamma, const float* __restrict__ beta){
  int gid = blockIdx.x*256 + threadIdx.x;  // exactly 1,179,648 float4s
  int o = (gid / 2304) & 63;
  float mean = bn[o] * (1.f/73728.f);
  float var = bn[64 + o] * (1.f/73728.f) - mean*mean;
  float inv = rsqrtf(var + 1e-5f);
  float g = gamma[o], be = beta[o];
  float4 v = ((const float4*)yb)[gid];
  v.x = fmaxf((v.x - mean)*inv*g + be, 0.f);
  v.y = fmaxf((v.y - mean)*inv*g + be, 0.f);
  v.z = fmaxf((v.z - mean)*inv*g + be, 0.f);
  v.w = fmaxf((v.w - mean)*inv*g + be, 0.f);
  ((float4*)yb)[gid] = v;
}

extern "C" void kernel_launch(void* const* d_in, const int* in_sizes, int n_in,
                              void* d_out, int out_size, void* d_ws, size_t ws_size,
                              hipStream_t stream) {
  const float* cen   = (const float*)d_in[0];
  const float* sumw  = (const float*)d_in[1];
  const float* qw    = (const float*)d_in[2];
  const float* kw    = (const float*)d_in[3];
  const float* vw    = (const float*)d_in[4];
  const float* ow    = (const float*)d_in[5];
  const float* gamma = (const float*)d_in[6];
  const float* beta  = (const float*)d_in[7];

  char* ws = (char*)d_ws;
  unsigned short* cenbf  = (unsigned short*)(ws + WS_CENPAD);
  unsigned short* Wb     = (unsigned short*)(ws + WS_W);
  unsigned short* qbf    = (unsigned short*)(ws + WS_Q);
  unsigned short* KV     = (unsigned short*)(ws + WS_KV);
  float*          spart  = (float*)(ws + WS_SPART);
  float*          kkp    = (float*)(ws + WS_KKP);
  float*          qqp    = (float*)(ws + WS_QQP);
  float*          attnT  = (float*)(ws + WS_ATTN);
  float*          outbuf = (float*)(ws + WS_OUT);
  float*          bn     = (float*)(ws + WS_BN);

  hipMemsetAsync(bn, 0, 128*sizeof(float), stream);
  pad_kernel    <<<25088, 256, 0, stream>>>(cen, cenbf);
  prep_kernel   <<<2304, 256, 0, stream>>>(sumw, kw, vw, Wb);
  qproj_kernel  <<<dim3(36, 8), 256, 0, stream>>>(cen, qw, qbf);
  conv_kv_mfma  <<<dim3(36, 1, 32), 512, 0, stream>>>(cenbf, Wb, KV);
  scores_kernel <<<dim3(9, 4, 8), 256, 0, stream>>>(KV, qbf, spart, kkp, qqp);
  softmax_kernel<<<32, 256, 0, stream>>>(spart, kkp, qqp, attnT);
  pv_kernel     <<<dim3(9, 4, 8), 256, 0, stream>>>(KV, attnT, outbuf);
  outconv_kernel<<<dim3(36, 8), 256, 0, stream>>>(outbuf, ow, (float*)d_out, bn);
  bnapply_kernel<<<4608, 256, 0, stream>>>((float*)d_out, bn, gamma, beta);
}

// Round 5
// 609.368 us; speedup vs baseline: 1.6952x; 1.6952x over previous
//
#include <hip/hip_runtime.h>
#include <hip/hip_bf16.h>

// ---------------- sizes ----------------
// B=8, C=64, H=W=96, S=9216, NH=4 (dil=1,2,4,8), NL=8, hid=16
// KV rows per (i,b): 256 (0..127 = K via k_w, 128..255 = V via v_w)
// conv GEMM per (i,b): [256 o] x [576 k = tap*64+c] x [9216 s], bf16 MFMA

// ---------------- workspace layout (bytes) ----------------
#define WS_CENPAD 0UL           // f32 [8][64][112][112]      = 25,690,112
#define WS_W      25690112UL    // bf16 [4][18][256][32]      =  1,179,648 (frag-ready)
#define WS_Q      28049408UL    // bf16 [8][64][9216]         =  9,437,184 (row = o*4+i)
#define WS_KV     46923776UL    // bf16 [4][8][256][9216]     = 150,994,944
#define WS_SPART  197918720UL   // f32 [288][2048]            =  2,359,296
#define WS_KKP    200278016UL   // f32 [288][128]             =    147,456
#define WS_QQP    200425472UL   // f32 [288][16]              =     18,432
#define WS_ATTN   200443904UL   // f32 [32][128][16]          =    262,144
#define WS_OUT    200706048UL   // f32 [8][64][9216]          = 18,874,368
#define WS_BN     219580416UL   // f32 [4][128] per-quarter partial sums

typedef __attribute__((ext_vector_type(8))) short short8;
typedef __attribute__((ext_vector_type(4))) float f32x4;

__device__ __forceinline__ float bflo(unsigned int u){ return __uint_as_float(u<<16); }
__device__ __forceinline__ float bfhi(unsigned int u){ return __uint_as_float(u & 0xffff0000u); }
__device__ __forceinline__ unsigned short f2bf(float f){
  unsigned int u = __float_as_uint(f);
  return (unsigned short)((u + 0x7fffu + ((u>>16)&1u)) >> 16);
}
__device__ __forceinline__ unsigned short fbits(float f){
  __hip_bfloat16 h = __float2bfloat16(f);
  return __builtin_bit_cast(unsigned short, h);
}

// ---- pad: cen [8,64,96,96] f32 -> cenpad [8,64,112,112] f32 (8-halo zeros)
__global__ __launch_bounds__(256) void pad_kernel(const float* __restrict__ cen, float* __restrict__ cenpad){
  int idx = blockIdx.x*256 + threadIdx.x;  // exactly 6,422,528 threads
  int px = idx % 112; int t = idx / 112; int py = t % 112; int bc = t / 112;
  int y = py - 8, x = px - 8;
  float v = 0.f;
  if (y >= 0 && y < 96 && x >= 0 && x < 96) v = cen[(size_t)bc*9216 + y*96 + x];
  cenpad[idx] = v;
}

// ---- prep: build conv weights in bf16, fragment-ready layout
// Wb[((i*18 + kc)*256 + o)*32 + k'] where k = t*64 + c, kc=k>>5, k'=k&31
__global__ __launch_bounds__(256) void prep_kernel(const float* __restrict__ sumw,
    const float* __restrict__ kw, const float* __restrict__ vw, unsigned short* __restrict__ Wb){
  int idx = blockIdx.x*256 + threadIdx.x;  // exactly 589,824
  int o = idx & 255; int r = idx >> 8; int c = r & 63; r >>= 6; int t = r % 9; int i = r / 9;
  float l0 = sumw[(i*64 + c)*2 + 0], l1 = sumw[(i*64 + c)*2 + 1];
  float m = fmaxf(l0, l1);
  float e0 = expf(l0 - m), e1 = expf(l1 - m);
  float inv = 1.f/(e0 + e1);
  float sw0 = e0*inv, sw1 = e1*inv;
  const float* wsrc = (o < 128) ? (kw + ((size_t)i*128 + o)*512 + c)
                                : (vw + ((size_t)i*128 + (o-128))*512 + c);
  float A = 0.f;
  #pragma unroll
  for (int j = 0; j < 8; ++j) A += wsrc[j*64];
  float val;
  if (t == 4) {
    val = A;  // center tap: all mixed kernels have weight 1 at center (sw0+sw1=1)
  } else {
    const int tmap[9] = {0,1,2,7,0,3,6,5,4};
    int j = tmap[t];
    val = -(wsrc[j*64]*sw0 + A*sw1*0.125f);
  }
  int k = t*64 + c;
  Wb[(((size_t)i*18 + (k>>5))*256 + o)*32 + (k&31)] = f2bf(val);
}

// ---- Q projection: read cen ONCE, compute all 4 shifts x 16 rows -> Q bf16
// qbf[b][row][s], row = o*4 + i  (global q-row order from the stack/reshape)
__global__ __launch_bounds__(256) void qproj_kernel(const float* __restrict__ cen,
    const float* __restrict__ qw, unsigned short* __restrict__ qbf){
  __shared__ float WT[64][64];  // [c][row]
  int tid = threadIdx.x;
  int st = blockIdx.x, b = blockIdx.y;
  #pragma unroll
  for (int e = 0; e < 16; ++e) {
    int f = e*256 + tid; int c = f >> 6, row = f & 63;
    int i = row & 3, o = row >> 2;
    WT[c][row] = qw[(size_t)i*1024 + o*64 + c];
  }
  __syncthreads();
  int s = st*256 + tid;
  float acc[64];
  #pragma unroll
  for (int r = 0; r < 64; ++r) acc[r] = 0.f;
  const float* cb = cen + (size_t)b*64*9216 + s;
  for (int c = 0; c < 64; ++c) {
    float xv = cb[(size_t)c*9216];
    #pragma unroll
    for (int r4 = 0; r4 < 16; ++r4) {
      float4 w = *(const float4*)&WT[c][r4*4];
      acc[r4*4+0] = fmaf(w.x, xv, acc[r4*4+0]);
      acc[r4*4+1] = fmaf(w.y, xv, acc[r4*4+1]);
      acc[r4*4+2] = fmaf(w.z, xv, acc[r4*4+2]);
      acc[r4*4+3] = fmaf(w.w, xv, acc[r4*4+3]);
    }
  }
  unsigned short* qb = qbf + (size_t)b*64*9216 + s;
  #pragma unroll
  for (int r = 0; r < 64; ++r) qb[(size_t)r*9216] = fbits(acc[r]);
}

// ---- conv K/V via MFMA: per (i,b) GEMM [256 o] x [576 k] x [9216 s] -> bf16 KV
// 256 thr = 4 waves (2 wm x 2 wn); tile O=128 x S=128; K chunks of 32.
// Per-iter issue order: A(k) -> pack_k -> gather(k+1) -> lgkm-only barrier ->
// ds_read -> MFMA. In-order vmcnt => MFMA waits vmcnt(4) (gather in flight),
// next pack waits vmcnt(4) (A in flight): counted-vmcnt pipeline, no drain.
// X gather: f32 image, float4 over 4 consecutive s (96%4==0 -> single row,
// dword-aligned for any dilation shift); reg-transpose -> bf16 LDS [128][72B].
__global__ __launch_bounds__(256, 2) void conv_kv_mfma(const float* __restrict__ cenpad,
    const unsigned short* __restrict__ Wb, unsigned short* __restrict__ KV){
  __shared__ char Xs[2][128*72];
  const int tid = threadIdx.x;
  const int st = blockIdx.x, oc = blockIdx.y, ib = blockIdx.z;
  const int i = ib >> 3, b = ib & 7;
  const int dil = 1 << i;
  const int s0 = st*128;
  const int wave = tid >> 6, lane = tid & 63;
  const int wm = wave >> 1, wn = wave & 1;
  const int l15 = lane & 15, l4 = lane >> 4;
  // staging mapping: thread = (sblk = tid>>3 [0..31], q = tid&7 [0..7])
  // covers s_local = sblk*4 .. +3  x  k' = q*4 .. +3
  const int sblk = tid >> 3, q = tid & 7;
  const int sl = sblk*4;
  const int s = s0 + sl;
  const int y = s / 96, x = s - y*96;
  const float* bp = cenpad + (size_t)b*802816 + (size_t)(y+8)*112 + (x+8);

  f32x4 acc[4][4];
  #pragma unroll
  for (int mf = 0; mf < 4; ++mf)
    #pragma unroll
    for (int nf = 0; nf < 4; ++nf)
      acc[mf][nf] = (f32x4){0.f, 0.f, 0.f, 0.f};

  const unsigned short* Wi = Wb + (size_t)i*18*8192;
  const unsigned short* apb = Wi + (size_t)(oc*128 + wm*64 + l15)*32 + l4*8;

  float4 g[4];
  auto gather = [&](int kn){
    int t = kn >> 1;
    int c0 = (kn & 1)*32 + q*4;
    int dy = (t/3 - 1)*dil, dx = (t - (t/3)*3 - 1)*dil;
    const float* p = bp + (size_t)c0*12544 + (dy*112 + dx);
    #pragma unroll
    for (int jc = 0; jc < 4; ++jc) g[jc] = *(const float4*)(p + (size_t)jc*12544);
  };

  gather(0);   // prologue
  int buf = 0;
  for (int kc = 0; kc < 18; ++kc) {
    // ---- 1. A fragments for this chunk (global, L2-resident; issued FIRST so
    //         the gather prefetch below stays behind it in the VMEM queue)
    short8 a[4];
    const unsigned short* ap = apb + (size_t)kc*8192;
    #pragma unroll
    for (int mf = 0; mf < 4; ++mf) a[mf] = *(const short8*)(ap + mf*512);
    asm volatile("" ::: "memory");
    // ---- 2. pack chunk-kc gather (reg transpose 4c x 4s -> [s][k']) & write LDS
    char* wp = Xs[buf] + sl*72 + q*8;
    const float* gf = (const float*)g;
    #pragma unroll
    for (int j = 0; j < 4; ++j) {
      unsigned int p0 = (unsigned int)fbits(gf[0*4+j]) | ((unsigned int)fbits(gf[1*4+j]) << 16);
      unsigned int p1 = (unsigned int)fbits(gf[2*4+j]) | ((unsigned int)fbits(gf[3*4+j]) << 16);
      *(uint2*)(wp + j*72) = make_uint2(p0, p1);
    }
    // ---- 3. prefetch next chunk's gather (stays in flight across barrier)
    if (kc < 17) gather(kc + 1);
    // ---- 4. LDS-only drain + raw barrier (NO vmcnt drain)
    asm volatile("s_waitcnt lgkmcnt(0)" ::: "memory");
    __builtin_amdgcn_s_barrier();
    asm volatile("" ::: "memory");
    // ---- 5. B fragments from LDS (72B rows -> conflict-free)
    short8 bfr[4];
    #pragma unroll
    for (int nf = 0; nf < 4; ++nf) {
      const char* rp = Xs[buf] + (wn*64 + nf*16 + l15)*72 + l4*16;
      uint2 lo = *(const uint2*)rp;
      uint2 hi = *(const uint2*)(rp + 8);
      uint4 tb = make_uint4(lo.x, lo.y, hi.x, hi.y);
      bfr[nf] = *(short8*)&tb;
    }
    // ---- 6. MFMA (waits lgkm for B, vmcnt(4) for A)
    #pragma unroll
    for (int mf = 0; mf < 4; ++mf)
      #pragma unroll
      for (int nf = 0; nf < 4; ++nf)
        acc[mf][nf] = __builtin_amdgcn_mfma_f32_16x16x32_bf16(a[mf], bfr[nf], acc[mf][nf], 0, 0, 0);
    buf ^= 1;
  }

  // ---- epilogue: C/D mapping row=(l>>4)*4+r, col=l&15
  #pragma unroll
  for (int mf = 0; mf < 4; ++mf) {
    #pragma unroll
    for (int nf = 0; nf < 4; ++nf) {
      int scol = s0 + wn*64 + nf*16 + l15;
      int obase = oc*128 + wm*64 + mf*16 + l4*4;
      #pragma unroll
      for (int r = 0; r < 4; ++r)
        KV[((size_t)ib*256 + obase + r)*9216 + scol] = fbits(acc[mf][nf][r]);
    }
  }
}

// ---- scores: per (b,hh,chunk of 1024 s): partial 16x128 dots + row sumsq
__global__ __launch_bounds__(256) void scores_kernel(const unsigned short* __restrict__ KV,
    const unsigned short* __restrict__ qbf, float* __restrict__ spart,
    float* __restrict__ kkpart, float* __restrict__ qqpart){
  __shared__ float Klds[64][128];  // [s][kr]
  __shared__ float Qlds[16][64];   // [qr][s]
  const int tid = threadIdx.x;
  const int chunk = blockIdx.x, hh = blockIdx.y, b = blockIdx.z;
  const int kr = tid & 127, qrg = (tid >> 7) * 8;
  float acc[8] = {0,0,0,0,0,0,0,0};
  float kacc = 0.f, qacc = 0.f;
  const int skr = tid >> 2;
  const int sq16 = (tid & 3) * 16;
  const int qrow = tid >> 4, qoff = (tid & 15) * 4;
  const unsigned short* qsrc = qbf + ((size_t)(b*64 + hh*16 + qrow))*9216;

  for (int sc = 0; sc < 16; ++sc) {
    int sb = chunk*1024 + sc*64;
    #pragma unroll
    for (int p = 0; p < 2; ++p) {
      int krr = p*64 + skr;
      int ii = krr & 3, oo = hh*32 + (krr >> 2);
      const unsigned short* src = KV + ((size_t)((ii*8 + b)*256 + oo))*9216 + sb + sq16;
      uint4 u0 = *(const uint4*)src;
      uint4 u1 = *(const uint4*)(src + 8);
      Klds[sq16+ 0][krr] = bflo(u0.x); Klds[sq16+ 1][krr] = bfhi(u0.x);
      Klds[sq16+ 2][krr] = bflo(u0.y); Klds[sq16+ 3][krr] = bfhi(u0.y);
      Klds[sq16+ 4][krr] = bflo(u0.z); Klds[sq16+ 5][krr] = bfhi(u0.z);
      Klds[sq16+ 6][krr] = bflo(u0.w); Klds[sq16+ 7][krr] = bfhi(u0.w);
      Klds[sq16+ 8][krr] = bflo(u1.x); Klds[sq16+ 9][krr] = bfhi(u1.x);
      Klds[sq16+10][krr] = bflo(u1.y); Klds[sq16+11][krr] = bfhi(u1.y);
      Klds[sq16+12][krr] = bflo(u1.z); Klds[sq16+13][krr] = bfhi(u1.z);
      Klds[sq16+14][krr] = bflo(u1.w); Klds[sq16+15][krr] = bfhi(u1.w);
    }
    {
      uint2 uq = *(const uint2*)(qsrc + sb + qoff);
      float4 qv = make_float4(bflo(uq.x), bfhi(uq.x), bflo(uq.y), bfhi(uq.y));
      *(float4*)&Qlds[qrow][qoff] = qv;
    }
    __syncthreads();
    #pragma unroll 4
    for (int s4 = 0; s4 < 16; ++s4) {
      float k0 = Klds[s4*4+0][kr], k1 = Klds[s4*4+1][kr];
      float k2 = Klds[s4*4+2][kr], k3 = Klds[s4*4+3][kr];
      if (tid < 128) kacc += k0*k0 + k1*k1 + k2*k2 + k3*k3;
      #pragma unroll
      for (int q = 0; q < 8; ++q) {
        float4 qv = *(const float4*)&Qlds[qrg + q][s4*4];
        acc[q] += k0*qv.x + k1*qv.y + k2*qv.z + k3*qv.w;
      }
      if (tid >= 128 && tid < 144) {
        float4 qv = *(const float4*)&Qlds[tid & 15][s4*4];
        qacc += qv.x*qv.x + qv.y*qv.y + qv.z*qv.z + qv.w*qv.w;
      }
    }
    __syncthreads();
  }
  int pb = (b*4 + hh)*9 + chunk;
  #pragma unroll
  for (int q = 0; q < 8; ++q) spart[(size_t)pb*2048 + (qrg+q)*128 + kr] = acc[q];
  if (tid < 128) kkpart[(size_t)pb*128 + tid] = kacc;
  if (tid >= 128 && tid < 144) qqpart[(size_t)pb*16 + (tid - 128)] = qacc;
}

// ---- softmax: reduce partials, l2-normalize scale, instance-norm, row softmax -> attnT[kr][qr]
__global__ __launch_bounds__(256) void softmax_kernel(const float* __restrict__ spart,
    const float* __restrict__ kkpart, const float* __restrict__ qqpart, float* __restrict__ attnT){
  const int pb = blockIdx.x, tid = threadIdx.x;
  const int qr = tid >> 4, g = tid & 15;
  __shared__ float kkl[128];
  __shared__ float qql[16];
  __shared__ float red[8];
  __shared__ float stats[2];
  float sv[8] = {0,0,0,0,0,0,0,0};
  for (int ch = 0; ch < 9; ++ch) {
    const float* p = spart + ((size_t)(pb*9 + ch))*2048 + qr*128 + g*8;
    #pragma unroll
    for (int e = 0; e < 8; ++e) sv[e] += p[e];
  }
  if (tid < 128) { float ssum = 0.f; for (int ch = 0; ch < 9; ++ch) ssum += kkpart[(size_t)(pb*9+ch)*128 + tid]; kkl[tid] = ssum; }
  if (tid < 16)  { float ssum = 0.f; for (int ch = 0; ch < 9; ++ch) ssum += qqpart[(size_t)(pb*9+ch)*16 + tid]; qql[tid] = ssum; }
  __syncthreads();
  float qn = fmaxf(sqrtf(qql[qr]), 1e-12f);
  float lsum = 0.f, lsq = 0.f;
  #pragma unroll
  for (int e = 0; e < 8; ++e) {
    float kn = fmaxf(sqrtf(kkl[g*8+e]), 1e-12f);
    float v = sv[e] / (qn * kn * 96.0f);
    sv[e] = v; lsum += v; lsq += v*v;
  }
  #pragma unroll
  for (int m = 1; m <= 32; m <<= 1) { lsum += __shfl_xor(lsum, m); lsq += __shfl_xor(lsq, m); }
  if ((tid & 63) == 0) { red[tid >> 6] = lsum; red[4 + (tid >> 6)] = lsq; }
  __syncthreads();
  if (tid == 0) {
    float ts = red[0]+red[1]+red[2]+red[3];
    float tq = red[4]+red[5]+red[6]+red[7];
    float mean = ts / 2048.0f;
    float var = tq / 2048.0f - mean*mean;
    stats[0] = mean; stats[1] = rsqrtf(var + 1e-5f);
  }
  __syncthreads();
  float mean = stats[0], inv = stats[1];
  float mx = -1e30f;
  #pragma unroll
  for (int e = 0; e < 8; ++e) { sv[e] = (sv[e] - mean) * inv; mx = fmaxf(mx, sv[e]); }
  #pragma unroll
  for (int m = 1; m <= 8; m <<= 1) mx = fmaxf(mx, __shfl_xor(mx, m));
  float es = 0.f;
  #pragma unroll
  for (int e = 0; e < 8; ++e) { sv[e] = expf(sv[e] - mx); es += sv[e]; }
  #pragma unroll
  for (int m = 1; m <= 8; m <<= 1) es += __shfl_xor(es, m);
  float rinv = 1.0f / es;
  #pragma unroll
  for (int e = 0; e < 8; ++e) attnT[(size_t)pb*2048 + (g*8+e)*16 + qr] = sv[e] * rinv;
}

// ---- PV: out[b][hh*16+qr][s] = sum_kr attn * V
__global__ __launch_bounds__(256) void pv_kernel(const unsigned short* __restrict__ KV,
    const float* __restrict__ attnT, float* __restrict__ outbuf){
  __shared__ float at[128][16];
  int tid = threadIdx.x;
  int st = blockIdx.x, hh = blockIdx.y, b = blockIdx.z;
  const float* ap = attnT + ((size_t)(b*4 + hh))*2048;
  #pragma unroll
  for (int e = 0; e < 8; ++e) ((float*)at)[e*256 + tid] = ap[e*256 + tid];
  __syncthreads();
  int sbase = st*1024 + tid*4;
  float acc[16][4];
  #pragma unroll
  for (int q = 0; q < 16; ++q)
    #pragma unroll
    for (int p = 0; p < 4; ++p) acc[q][p] = 0.f;
  #pragma unroll 2
  for (int kr = 0; kr < 128; ++kr) {
    int ii = kr & 3, oo = 128 + hh*32 + (kr >> 2);
    const unsigned short* vp = KV + ((size_t)((ii*8 + b)*256 + oo))*9216 + sbase;
    uint2 u = *(const uint2*)vp;
    float v0 = bflo(u.x), v1 = bfhi(u.x), v2 = bflo(u.y), v3 = bfhi(u.y);
    #pragma unroll
    for (int q4 = 0; q4 < 4; ++q4) {
      float4 a = *(const float4*)&at[kr][q4*4];
      float av[4] = {a.x, a.y, a.z, a.w};
      #pragma unroll
      for (int j = 0; j < 4; ++j) {
        acc[q4*4+j][0] = fmaf(av[j], v0, acc[q4*4+j][0]);
        acc[q4*4+j][1] = fmaf(av[j], v1, acc[q4*4+j][1]);
        acc[q4*4+j][2] = fmaf(av[j], v2, acc[q4*4+j][2]);
        acc[q4*4+j][3] = fmaf(av[j], v3, acc[q4*4+j][3]);
      }
    }
  }
  float* ob = outbuf + ((size_t)(b*64 + hh*16))*9216 + sbase;
  #pragma unroll
  for (int q = 0; q < 16; ++q) {
    float4 w = make_float4(acc[q][0], acc[q][1], acc[q][2], acc[q][3]);
    *(float4*)(ob + (size_t)q*9216) = w;
  }
}

// ---- 1x1 out conv -> d_out (pre-BN), no atomics
__global__ __launch_bounds__(256) void outconv_kernel(const float* __restrict__ outbuf,
    const float* __restrict__ ow, float* __restrict__ dout){
  __shared__ float WT[64][64];  // [c][o]
  int tid = threadIdx.x; int st = blockIdx.x; int b = blockIdx.y;
  #pragma unroll
  for (int e = 0; e < 16; ++e) {
    int f = e*256 + tid; int c = f >> 6, o = f & 63;
    WT[c][o] = ow[o*64 + c];
  }
  __syncthreads();
  int s = st*256 + tid;
  float acc[64];
  #pragma unroll
  for (int o = 0; o < 64; ++o) acc[o] = 0.f;
  for (int c = 0; c < 64; ++c) {
    float xv = outbuf[((size_t)(b*64 + c))*9216 + s];
    #pragma unroll
    for (int o4 = 0; o4 < 16; ++o4) {
      float4 w = *(const float4*)&WT[c][o4*4];
      acc[o4*4+0] = fmaf(w.x, xv, acc[o4*4+0]);
      acc[o4*4+1] = fmaf(w.y, xv, acc[o4*4+1]);
      acc[o4*4+2] = fmaf(w.z, xv, acc[o4*4+2]);
      acc[o4*4+3] = fmaf(w.w, xv, acc[o4*4+3]);
    }
  }
  #pragma unroll
  for (int o = 0; o < 64; ++o) dout[((size_t)(b*64 + o))*9216 + s] = acc[o];
}

// ---- BN partial stats: grid (64 ch, 4 quarters) -> bnpart[qt][{sum,sq}]
__global__ __launch_bounds__(256) void bnstats_kernel(const float* __restrict__ yb, float* __restrict__ bnpart){
  int o = blockIdx.x, qt = blockIdx.y, tid = threadIdx.x;
  float s = 0.f, sq = 0.f;
  for (int k = tid; k < 18432; k += 256) {
    int f = qt*18432 + k;
    int b = f / 9216, sp = f - b*9216;
    float v = yb[((size_t)(b*64 + o))*9216 + sp];
    s += v; sq += v*v;
  }
  #pragma unroll
  for (int m = 1; m <= 32; m <<= 1) { s += __shfl_xor(s, m); sq += __shfl_xor(sq, m); }
  __shared__ float r0[4], r1[4];
  if ((tid & 63) == 0) { r0[tid >> 6] = s; r1[tid >> 6] = sq; }
  __syncthreads();
  if (tid == 0) {
    bnpart[qt*128 + o]      = r0[0]+r0[1]+r0[2]+r0[3];
    bnpart[qt*128 + 64 + o] = r1[0]+r1[1]+r1[2]+r1[3];
  }
}

// ---- BN apply + ReLU (in place on d_out), float4; combines 4 partials
__global__ __launch_bounds__(256) void bnapply_kernel(float* __restrict__ yb,
    const float* __restrict__ bnpart, const float* __restrict__ gamma, const float* __restrict__ beta){
  int gid = blockIdx.x*256 + threadIdx.x;  // exactly 1,179,648 float4s
  int o = (gid / 2304) & 63;
  float ts = 0.f, tq = 0.f;
  #pragma unroll
  for (int qt = 0; qt < 4; ++qt) { ts += bnpart[qt*128 + o]; tq += bnpart[qt*128 + 64 + o]; }
  float mean = ts * (1.f/73728.f);
  float var = tq * (1.f/73728.f) - mean*mean;
  float inv = rsqrtf(var + 1e-5f);
  float g = gamma[o], be = beta[o];
  float4 v = ((const float4*)yb)[gid];
  v.x = fmaxf((v.x - mean)*inv*g + be, 0.f);
  v.y = fmaxf((v.y - mean)*inv*g + be, 0.f);
  v.z = fmaxf((v.z - mean)*inv*g + be, 0.f);
  v.w = fmaxf((v.w - mean)*inv*g + be, 0.f);
  ((float4*)yb)[gid] = v;
}

extern "C" void kernel_launch(void* const* d_in, const int* in_sizes, int n_in,
                              void* d_out, int out_size, void* d_ws, size_t ws_size,
                              hipStream_t stream) {
  const float* cen   = (const float*)d_in[0];
  const float* sumw  = (const float*)d_in[1];
  const float* qw    = (const float*)d_in[2];
  const float* kw    = (const float*)d_in[3];
  const float* vw    = (const float*)d_in[4];
  const float* ow    = (const float*)d_in[5];
  const float* gamma = (const float*)d_in[6];
  const float* beta  = (const float*)d_in[7];

  char* ws = (char*)d_ws;
  float*          cenpad = (float*)(ws + WS_CENPAD);
  unsigned short* Wb     = (unsigned short*)(ws + WS_W);
  unsigned short* qbf    = (unsigned short*)(ws + WS_Q);
  unsigned short* KV     = (unsigned short*)(ws + WS_KV);
  float*          spart  = (float*)(ws + WS_SPART);
  float*          kkp    = (float*)(ws + WS_KKP);
  float*          qqp    = (float*)(ws + WS_QQP);
  float*          attnT  = (float*)(ws + WS_ATTN);
  float*          outbuf = (float*)(ws + WS_OUT);
  float*          bnp    = (float*)(ws + WS_BN);

  pad_kernel    <<<25088, 256, 0, stream>>>(cen, cenpad);
  prep_kernel   <<<2304, 256, 0, stream>>>(sumw, kw, vw, Wb);
  qproj_kernel  <<<dim3(36, 8), 256, 0, stream>>>(cen, qw, qbf);
  conv_kv_mfma  <<<dim3(72, 2, 32), 256, 0, stream>>>(cenpad, Wb, KV);
  scores_kernel <<<dim3(9, 4, 8), 256, 0, stream>>>(KV, qbf, spart, kkp, qqp);
  softmax_kernel<<<32, 256, 0, stream>>>(spart, kkp, qqp, attnT);
  pv_kernel     <<<dim3(9, 4, 8), 256, 0, stream>>>(KV, attnT, outbuf);
  outconv_kernel<<<dim3(36, 8), 256, 0, stream>>>(outbuf, ow, (float*)d_out);
  bnstats_kernel<<<dim3(64, 4), 256, 0, stream>>>((const float*)d_out, bnp);
  bnapply_kernel<<<4608, 256, 0, stream>>>((float*)d_out, bnp, gamma, beta);
}

// Round 7
// 441.890 us; speedup vs baseline: 2.3377x; 1.3790x over previous
//
#include <hip/hip_runtime.h>
#include <hip/hip_bf16.h>

// ---------------- sizes ----------------
// B=8, C=64, H=W=96, S=9216, NH=4 (dil=1,2,4,8), NL=8, hid=16
// KV rows per (i,b): 256 (0..127 = K via k_w, 128..255 = V via v_w)
// conv GEMM per (i,b): [256 o] x [576 k = tap*64+c] x [9216 s], bf16 MFMA

// ---------------- workspace layout (bytes) ----------------
#define WS_CEN    0UL           // bf16 [8][64][112][112]     = 12,845,056
#define WS_SPART  12845056UL    // f32 [576][2048]            =  4,718,592
#define WS_W      25690112UL    // bf16 [4][18][256][32]      =  1,179,648 (frag-ready)
#define WS_Q      28049408UL    // bf16 [8][64][9216]         =  9,437,184 (row = o*4+i)
#define WS_KV     46923776UL    // bf16 [4][8][256][9216]     = 150,994,944
#define WS_KKP    197918720UL   // f32 [576][128]             =    294,912
#define WS_QQP    198213632UL   // f32 [576][16]              =     36,864
#define WS_ATTN   198250496UL   // f32 [32][128][16]          =    262,144
#define WS_OUT    198512640UL   // f32 [8][64][9216]          = 18,874,368
#define WS_BN     217387008UL   // f32 [4][128] per-quarter partial sums

typedef __attribute__((ext_vector_type(8))) short short8;
typedef __attribute__((ext_vector_type(4))) float f32x4;

__device__ __forceinline__ float bflo(unsigned int u){ return __uint_as_float(u<<16); }
__device__ __forceinline__ float bfhi(unsigned int u){ return __uint_as_float(u & 0xffff0000u); }
__device__ __forceinline__ unsigned short f2bf(float f){
  unsigned int u = __float_as_uint(f);
  return (unsigned short)((u + 0x7fffu + ((u>>16)&1u)) >> 16);
}
__device__ __forceinline__ unsigned short fbits(float f){
  __hip_bfloat16 h = __float2bfloat16(f);
  return __builtin_bit_cast(unsigned short, h);
}

// ---- pad: cen [8,64,96,96] f32 -> cenbf [8,64,112,112] bf16 (8-halo zeros)
__global__ __launch_bounds__(256) void pad_kernel(const float* __restrict__ cen, unsigned short* __restrict__ cenbf){
  int idx = blockIdx.x*256 + threadIdx.x;  // exactly 6,422,528 threads
  int px = idx % 112; int t = idx / 112; int py = t % 112; int bc = t / 112;
  int y = py - 8, x = px - 8;
  float v = 0.f;
  if (y >= 0 && y < 96 && x >= 0 && x < 96) v = cen[(size_t)bc*9216 + y*96 + x];
  cenbf[idx] = fbits(v);
}

// ---- prep: build conv weights in bf16, fragment-ready layout
// Wb[((i*18 + kc)*256 + o)*32 + k'] where k = t*64 + c, kc=k>>5, k'=k&31
__global__ __launch_bounds__(256) void prep_kernel(const float* __restrict__ sumw,
    const float* __restrict__ kw, const float* __restrict__ vw, unsigned short* __restrict__ Wb){
  int idx = blockIdx.x*256 + threadIdx.x;  // exactly 589,824
  int o = idx & 255; int r = idx >> 8; int c = r & 63; r >>= 6; int t = r % 9; int i = r / 9;
  float l0 = sumw[(i*64 + c)*2 + 0], l1 = sumw[(i*64 + c)*2 + 1];
  float m = fmaxf(l0, l1);
  float e0 = expf(l0 - m), e1 = expf(l1 - m);
  float inv = 1.f/(e0 + e1);
  float sw0 = e0*inv, sw1 = e1*inv;
  const float* wsrc = (o < 128) ? (kw + ((size_t)i*128 + o)*512 + c)
                                : (vw + ((size_t)i*128 + (o-128))*512 + c);
  float A = 0.f;
  #pragma unroll
  for (int j = 0; j < 8; ++j) A += wsrc[j*64];
  float val;
  if (t == 4) {
    val = A;  // center tap: all mixed kernels have weight 1 at center (sw0+sw1=1)
  } else {
    const int tmap[9] = {0,1,2,7,0,3,6,5,4};
    int j = tmap[t];
    val = -(wsrc[j*64]*sw0 + A*sw1*0.125f);
  }
  int k = t*64 + c;
  Wb[(((size_t)i*18 + (k>>5))*256 + o)*32 + (k&31)] = f2bf(val);
}

// ---- Q projection: read cen ONCE, compute all 4 shifts x 16 rows -> Q bf16
// qbf[b][row][s], row = o*4 + i  (global q-row order from the stack/reshape)
__global__ __launch_bounds__(256) void qproj_kernel(const float* __restrict__ cen,
    const float* __restrict__ qw, unsigned short* __restrict__ qbf){
  __shared__ float WT[64][64];  // [c][row]
  int tid = threadIdx.x;
  int st = blockIdx.x, b = blockIdx.y;
  #pragma unroll
  for (int e = 0; e < 16; ++e) {
    int f = e*256 + tid; int c = f >> 6, row = f & 63;
    int i = row & 3, o = row >> 2;
    WT[c][row] = qw[(size_t)i*1024 + o*64 + c];
  }
  __syncthreads();
  int s = st*256 + tid;
  float acc[64];
  #pragma unroll
  for (int r = 0; r < 64; ++r) acc[r] = 0.f;
  const float* cb = cen + (size_t)b*64*9216 + s;
  for (int c = 0; c < 64; ++c) {
    float xv = cb[(size_t)c*9216];
    #pragma unroll
    for (int r4 = 0; r4 < 16; ++r4) {
      float4 w = *(const float4*)&WT[c][r4*4];
      acc[r4*4+0] = fmaf(w.x, xv, acc[r4*4+0]);
      acc[r4*4+1] = fmaf(w.y, xv, acc[r4*4+1]);
      acc[r4*4+2] = fmaf(w.z, xv, acc[r4*4+2]);
      acc[r4*4+3] = fmaf(w.w, xv, acc[r4*4+3]);
    }
  }
  unsigned short* qb = qbf + (size_t)b*64*9216 + s;
  #pragma unroll
  for (int r = 0; r < 64; ++r) qb[(size_t)r*9216] = fbits(acc[r]);
}

// ---- conv K/V via MFMA: per (i,b) GEMM [256 o] x [576 k] x [9216 s] -> bf16 KV
// R3 structure (512 thr = 8 waves 2x4, tile O=256 x S=256, K chunks of 32,
// bf16 scalar gather, proven conflict-free LDS pattern) with FIXED issue order:
// A(k) -> pack_k (waits vmcnt(8): gather_k only) -> gather(k+1) -> lgkm-only
// barrier -> ds_read -> MFMA (waits vmcnt(16): A_k retired, gather_{k+1} in
// flight). In-order vmcnt retirement => nothing ever drains to 0.
__global__ __launch_bounds__(512, 2) void conv_kv_mfma(const unsigned short* __restrict__ cenbf,
    const unsigned short* __restrict__ Wb, unsigned short* __restrict__ KV){
  __shared__ char Xs[2][256*72];
  const int tid = threadIdx.x;
  const int st = blockIdx.x, ib = blockIdx.z;
  const int i = ib >> 3, b = ib & 7;
  const int dil = 1 << i;
  const int s0 = st*256;
  const int wave = tid >> 6, lane = tid & 63;
  const int wm = wave >> 2, wn = wave & 3;
  const int l15 = lane & 15, l4 = lane >> 4;
  // staging mapping: thread covers (s_idx, k' = khalf*16 .. +15)
  const int s_idx = tid & 255;
  const int khalf = tid >> 8;
  const int s = s0 + s_idx;
  const int y = s / 96, x = s - y*96;
  const unsigned short* cb = cenbf + (size_t)b*802816 + (size_t)(y+8)*112 + (x+8);

  f32x4 acc[8][4];
  #pragma unroll
  for (int mf = 0; mf < 8; ++mf)
    #pragma unroll
    for (int nf = 0; nf < 4; ++nf)
      acc[mf][nf] = (f32x4){0.f, 0.f, 0.f, 0.f};

  const unsigned short* Wi = Wb + (size_t)i*18*8192;
  const unsigned short* apb = Wi + (size_t)(wm*128 + l15)*32 + l4*8;

  unsigned short vs[16];
  auto gather = [&](int kn){
    int t = kn >> 1;
    int cbase = (kn & 1)*32 + khalf*16;
    int dy = (t/3 - 1)*dil, dx = (t - (t/3)*3 - 1)*dil;
    const unsigned short* p = cb + (size_t)cbase*12544 + (dy*112 + dx);
    #pragma unroll
    for (int j = 0; j < 16; ++j) vs[j] = p[(size_t)j*12544];
  };

  gather(0);   // prologue
  int buf = 0;
  for (int kc = 0; kc < 18; ++kc) {
    // ---- 1. A fragments first (so waiting for A never drains the prefetch)
    short8 a[8];
    const unsigned short* ap = apb + (size_t)kc*8192;
    #pragma unroll
    for (int mf = 0; mf < 8; ++mf) a[mf] = *(const short8*)(ap + mf*512);
    asm volatile("" ::: "memory");   // pin A-loads before pack/gather
    // ---- 2. pack chunk-kc gather & write LDS buf (vmcnt(8): gather_k only)
    char* wp = Xs[buf] + s_idx*72 + khalf*32;
    #pragma unroll
    for (int w = 0; w < 4; ++w) {
      unsigned int p0 = (unsigned int)vs[4*w+0] | ((unsigned int)vs[4*w+1] << 16);
      unsigned int p1 = (unsigned int)vs[4*w+2] | ((unsigned int)vs[4*w+3] << 16);
      *(uint2*)(wp + w*8) = make_uint2(p0, p1);
    }
    // ---- 3. prefetch next chunk's gather (register WAR on vs pins order)
    if (kc < 17) gather(kc + 1);
    // ---- 4. LDS-only drain + raw barrier (NO vmcnt drain)
    asm volatile("s_waitcnt lgkmcnt(0)" ::: "memory");
    __builtin_amdgcn_s_barrier();
    asm volatile("" ::: "memory");
    // ---- 5. B fragments from LDS (72B rows -> conflict-free, measured R3)
    short8 bfr[4];
    #pragma unroll
    for (int nf = 0; nf < 4; ++nf) {
      const char* rp = Xs[buf] + (wn*64 + nf*16 + l15)*72 + l4*16;
      uint2 lo = *(const uint2*)rp;
      uint2 hi = *(const uint2*)(rp + 8);
      uint4 tb = make_uint4(lo.x, lo.y, hi.x, hi.y);
      bfr[nf] = *(short8*)&tb;
    }
    // ---- 6. MFMA (lgkm for B, vmcnt(16) for A)
    #pragma unroll
    for (int mf = 0; mf < 8; ++mf)
      #pragma unroll
      for (int nf = 0; nf < 4; ++nf)
        acc[mf][nf] = __builtin_amdgcn_mfma_f32_16x16x32_bf16(a[mf], bfr[nf], acc[mf][nf], 0, 0, 0);
    buf ^= 1;
  }

  // ---- epilogue: C/D mapping row=(l>>4)*4+r, col=l&15
  #pragma unroll
  for (int mf = 0; mf < 8; ++mf) {
    #pragma unroll
    for (int nf = 0; nf < 4; ++nf) {
      int scol = s0 + wn*64 + nf*16 + l15;
      int obase = wm*128 + mf*16 + l4*4;
      #pragma unroll
      for (int r = 0; r < 4; ++r)
        KV[((size_t)ib*256 + obase + r)*9216 + scol] = fbits(acc[mf][nf][r]);
    }
  }
}

// ---- scores via MFMA, zero LDS staging: reduction dim (s) is contiguous for
// both Q[16][S] and K[128][S] -> A/B frags are direct global short8 loads.
// kk/qq row-sumsq come free as diagonals of mfma(K,K)/mfma(Q,Q).
// grid (18 chunks, 4 hh, 8 b), 256 thr = 4 waves; wave covers 128 s = 4 slices.
// Per-wave LDS layout: [0,2048) scores, [2048,2176) kk, [2176,2192) qq.
__global__ __launch_bounds__(256) void scores_mfma(const unsigned short* __restrict__ KV,
    const unsigned short* __restrict__ qbf, float* __restrict__ spart,
    float* __restrict__ kkpart, float* __restrict__ qqpart){
  __shared__ float red[4][2192];  // per-wave: 2048 scores + 128 kk + 16 qq
  const int tid = threadIdx.x;
  const int chunk = blockIdx.x, hh = blockIdx.y, b = blockIdx.z;
  const int wave = tid >> 6, lane = tid & 63;
  const int l15 = lane & 15, l4 = lane >> 4;
  const int sbase = chunk*512 + wave*128;

  const unsigned short* qp = qbf + ((size_t)(b*64 + hh*16 + l15))*9216 + sbase + l4*8;
  // K row kr = nf*16 + l15: i = l15&3 (const over nf), ch = hh*32 + nf*4 + (l15>>2)
  const unsigned short* kp = KV + ((size_t)(((l15&3)*8 + b)*256 + hh*32 + (l15>>2)))*9216 + sbase + l4*8;

  f32x4 sacc[8], kkacc[8], qqacc;
  #pragma unroll
  for (int nf = 0; nf < 8; ++nf) { sacc[nf] = (f32x4){0,0,0,0}; kkacc[nf] = (f32x4){0,0,0,0}; }
  qqacc = (f32x4){0,0,0,0};

  #pragma unroll
  for (int sl = 0; sl < 4; ++sl) {
    short8 qf = *(const short8*)(qp + sl*32);
    short8 kf[8];
    #pragma unroll
    for (int nf = 0; nf < 8; ++nf) kf[nf] = *(const short8*)(kp + (size_t)nf*36864 + sl*32);
    qqacc = __builtin_amdgcn_mfma_f32_16x16x32_bf16(qf, qf, qqacc, 0, 0, 0);
    #pragma unroll
    for (int nf = 0; nf < 8; ++nf) {
      sacc[nf]  = __builtin_amdgcn_mfma_f32_16x16x32_bf16(qf, kf[nf], sacc[nf], 0, 0, 0);
      kkacc[nf] = __builtin_amdgcn_mfma_f32_16x16x32_bf16(kf[nf], kf[nf], kkacc[nf], 0, 0, 0);
    }
  }
  // per-wave partials to LDS: D row=(l4*4+r)=q, col=l15 (kr within tile)
  float* rw = red[wave];
  #pragma unroll
  for (int nf = 0; nf < 8; ++nf)
    #pragma unroll
    for (int r = 0; r < 4; ++r)
      rw[(l4*4 + r)*128 + nf*16 + l15] = sacc[nf][r];
  if ((l15 >> 2) == l4) {          // diagonal lanes: row == col == l15
    int r = l15 & 3;
    #pragma unroll
    for (int nf = 0; nf < 8; ++nf) rw[2048 + nf*16 + l15] = kkacc[nf][r];
    rw[2176 + l15] = qqacc[r];
  }
  __syncthreads();
  int pb = (b*4 + hh)*18 + chunk;
  for (int t = tid; t < 2192; t += 256) {
    float v = red[0][t] + red[1][t] + red[2][t] + red[3][t];
    if (t < 2048)       spart[(size_t)pb*2048 + t] = v;
    else if (t < 2176)  kkpart[(size_t)pb*128 + (t - 2048)] = v;
    else                qqpart[(size_t)pb*16 + (t - 2176)] = v;
  }
}

// ---- softmax: reduce partials, l2-normalize scale, instance-norm, row softmax -> attnT[kr][qr]
__global__ __launch_bounds__(256) void softmax_kernel(const float* __restrict__ spart,
    const float* __restrict__ kkpart, const float* __restrict__ qqpart, float* __restrict__ attnT){
  const int pb = blockIdx.x, tid = threadIdx.x;
  const int qr = tid >> 4, g = tid & 15;
  __shared__ float kkl[128];
  __shared__ float qql[16];
  __shared__ float red[8];
  __shared__ float stats[2];
  float sv[8] = {0,0,0,0,0,0,0,0};
  for (int ch = 0; ch < 18; ++ch) {
    const float* p = spart + ((size_t)(pb*18 + ch))*2048 + qr*128 + g*8;
    #pragma unroll
    for (int e = 0; e < 8; ++e) sv[e] += p[e];
  }
  if (tid < 128) { float ssum = 0.f; for (int ch = 0; ch < 18; ++ch) ssum += kkpart[(size_t)(pb*18+ch)*128 + tid]; kkl[tid] = ssum; }
  if (tid < 16)  { float ssum = 0.f; for (int ch = 0; ch < 18; ++ch) ssum += qqpart[(size_t)(pb*18+ch)*16 + tid]; qql[tid] = ssum; }
  __syncthreads();
  float qn = fmaxf(sqrtf(qql[qr]), 1e-12f);
  float lsum = 0.f, lsq = 0.f;
  #pragma unroll
  for (int e = 0; e < 8; ++e) {
    float kn = fmaxf(sqrtf(kkl[g*8+e]), 1e-12f);
    float v = sv[e] / (qn * kn * 96.0f);
    sv[e] = v; lsum += v; lsq += v*v;
  }
  #pragma unroll
  for (int m = 1; m <= 32; m <<= 1) { lsum += __shfl_xor(lsum, m); lsq += __shfl_xor(lsq, m); }
  if ((tid & 63) == 0) { red[tid >> 6] = lsum; red[4 + (tid >> 6)] = lsq; }
  __syncthreads();
  if (tid == 0) {
    float ts = red[0]+red[1]+red[2]+red[3];
    float tq = red[4]+red[5]+red[6]+red[7];
    float mean = ts / 2048.0f;
    float var = tq / 2048.0f - mean*mean;
    stats[0] = mean; stats[1] = rsqrtf(var + 1e-5f);
  }
  __syncthreads();
  float mean = stats[0], inv = stats[1];
  float mx = -1e30f;
  #pragma unroll
  for (int e = 0; e < 8; ++e) { sv[e] = (sv[e] - mean) * inv; mx = fmaxf(mx, sv[e]); }
  #pragma unroll
  for (int m = 1; m <= 8; m <<= 1) mx = fmaxf(mx, __shfl_xor(mx, m));
  float es = 0.f;
  #pragma unroll
  for (int e = 0; e < 8; ++e) { sv[e] = expf(sv[e] - mx); es += sv[e]; }
  #pragma unroll
  for (int m = 1; m <= 8; m <<= 1) es += __shfl_xor(es, m);
  float rinv = 1.0f / es;
  #pragma unroll
  for (int e = 0; e < 8; ++e) attnT[(size_t)pb*2048 + (g*8+e)*16 + qr] = sv[e] * rinv;
}

// ---- PV: out[b][hh*16+qr][s] = sum_kr attn * V
__global__ __launch_bounds__(256) void pv_kernel(const unsigned short* __restrict__ KV,
    const float* __restrict__ attnT, float* __restrict__ outbuf){
  __shared__ float at[128][16];
  int tid = threadIdx.x;
  int st = blockIdx.x, hh = blockIdx.y, b = blockIdx.z;
  const float* ap = attnT + ((size_t)(b*4 + hh))*2048;
  #pragma unroll
  for (int e = 0; e < 8; ++e) ((float*)at)[e*256 + tid] = ap[e*256 + tid];
  __syncthreads();
  int sbase = st*1024 + tid*4;
  float acc[16][4];
  #pragma unroll
  for (int q = 0; q < 16; ++q)
    #pragma unroll
    for (int p = 0; p < 4; ++p) acc[q][p] = 0.f;
  #pragma unroll 2
  for (int kr = 0; kr < 128; ++kr) {
    int ii = kr & 3, oo = 128 + hh*32 + (kr >> 2);
    const unsigned short* vp = KV + ((size_t)((ii*8 + b)*256 + oo))*9216 + sbase;
    uint2 u = *(const uint2*)vp;
    float v0 = bflo(u.x), v1 = bfhi(u.x), v2 = bflo(u.y), v3 = bfhi(u.y);
    #pragma unroll
    for (int q4 = 0; q4 < 4; ++q4) {
      float4 a = *(const float4*)&at[kr][q4*4];
      float av[4] = {a.x, a.y, a.z, a.w};
      #pragma unroll
      for (int j = 0; j < 4; ++j) {
        acc[q4*4+j][0] = fmaf(av[j], v0, acc[q4*4+j][0]);
        acc[q4*4+j][1] = fmaf(av[j], v1, acc[q4*4+j][1]);
        acc[q4*4+j][2] = fmaf(av[j], v2, acc[q4*4+j][2]);
        acc[q4*4+j][3] = fmaf(av[j], v3, acc[q4*4+j][3]);
      }
    }
  }
  float* ob = outbuf + ((size_t)(b*64 + hh*16))*9216 + sbase;
  #pragma unroll
  for (int q = 0; q < 16; ++q) {
    float4 w = make_float4(acc[q][0], acc[q][1], acc[q][2], acc[q][3]);
    *(float4*)(ob + (size_t)q*9216) = w;
  }
}

// ---- 1x1 out conv -> d_out (pre-BN), no atomics
__global__ __launch_bounds__(256) void outconv_kernel(const float* __restrict__ outbuf,
    const float* __restrict__ ow, float* __restrict__ dout){
  __shared__ float WT[64][64];  // [c][o]
  int tid = threadIdx.x; int st = blockIdx.x; int b = blockIdx.y;
  #pragma unroll
  for (int e = 0; e < 16; ++e) {
    int f = e*256 + tid; int c = f >> 6, o = f & 63;
    WT[c][o] = ow[o*64 + c];
  }
  __syncthreads();
  int s = st*256 + tid;
  float acc[64];
  #pragma unroll
  for (int o = 0; o < 64; ++o) acc[o] = 0.f;
  for (int c = 0; c < 64; ++c) {
    float xv = outbuf[((size_t)(b*64 + c))*9216 + s];
    #pragma unroll
    for (int o4 = 0; o4 < 16; ++o4) {
      float4 w = *(const float4*)&WT[c][o4*4];
      acc[o4*4+0] = fmaf(w.x, xv, acc[o4*4+0]);
      acc[o4*4+1] = fmaf(w.y, xv, acc[o4*4+1]);
      acc[o4*4+2] = fmaf(w.z, xv, acc[o4*4+2]);
      acc[o4*4+3] = fmaf(w.w, xv, acc[o4*4+3]);
    }
  }
  #pragma unroll
  for (int o = 0; o < 64; ++o) dout[((size_t)(b*64 + o))*9216 + s] = acc[o];
}

// ---- BN partial stats: grid (64 ch, 4 quarters) -> bnpart[qt][{sum,sq}]
__global__ __launch_bounds__(256) void bnstats_kernel(const float* __restrict__ yb, float* __restrict__ bnpart){
  int o = blockIdx.x, qt = blockIdx.y, tid = threadIdx.x;
  float s = 0.f, sq = 0.f;
  for (int k = tid; k < 18432; k += 256) {
    int f = qt*18432 + k;
    int b = f / 9216, sp = f - b*9216;
    float v = yb[((size_t)(b*64 + o))*9216 + sp];
    s += v; sq += v*v;
  }
  #pragma unroll
  for (int m = 1; m <= 32; m <<= 1) { s += __shfl_xor(s, m); sq += __shfl_xor(sq, m); }
  __shared__ float r0[4], r1[4];
  if ((tid & 63) == 0) { r0[tid >> 6] = s; r1[tid >> 6] = sq; }
  __syncthreads();
  if (tid == 0) {
    bnpart[qt*128 + o]      = r0[0]+r0[1]+r0[2]+r0[3];
    bnpart[qt*128 + 64 + o] = r1[0]+r1[1]+r1[2]+r1[3];
  }
}

// ---- BN apply + ReLU (in place on d_out), float4; combines 4 partials
__global__ __launch_bounds__(256) void bnapply_kernel(float* __restrict__ yb,
    const float* __restrict__ bnpart, const float* __restrict__ gamma, const float* __restrict__ beta){
  int gid = blockIdx.x*256 + threadIdx.x;  // exactly 1,179,648 float4s
  int o = (gid / 2304) & 63;
  float ts = 0.f, tq = 0.f;
  #pragma unroll
  for (int qt = 0; qt < 4; ++qt) { ts += bnpart[qt*128 + o]; tq += bnpart[qt*128 + 64 + o]; }
  float mean = ts * (1.f/73728.f);
  float var = tq * (1.f/73728.f) - mean*mean;
  float inv = rsqrtf(var + 1e-5f);
  float g = gamma[o], be = beta[o];
  float4 v = ((const float4*)yb)[gid];
  v.x = fmaxf((v.x - mean)*inv*g + be, 0.f);
  v.y = fmaxf((v.y - mean)*inv*g + be, 0.f);
  v.z = fmaxf((v.z - mean)*inv*g + be, 0.f);
  v.w = fmaxf((v.w - mean)*inv*g + be, 0.f);
  ((float4*)yb)[gid] = v;
}

extern "C" void kernel_launch(void* const* d_in, const int* in_sizes, int n_in,
                              void* d_out, int out_size, void* d_ws, size_t ws_size,
                              hipStream_t stream) {
  const float* cen   = (const float*)d_in[0];
  const float* sumw  = (const float*)d_in[1];
  const float* qw    = (const float*)d_in[2];
  const float* kw    = (const float*)d_in[3];
  const float* vw    = (const float*)d_in[4];
  const float* ow    = (const float*)d_in[5];
  const float* gamma = (const float*)d_in[6];
  const float* beta  = (const float*)d_in[7];

  char* ws = (char*)d_ws;
  unsigned short* cenbf  = (unsigned short*)(ws + WS_CEN);
  float*          spart  = (float*)(ws + WS_SPART);
  unsigned short* Wb     = (unsigned short*)(ws + WS_W);
  unsigned short* qbf    = (unsigned short*)(ws + WS_Q);
  unsigned short* KV     = (unsigned short*)(ws + WS_KV);
  float*          kkp    = (float*)(ws + WS_KKP);
  float*          qqp    = (float*)(ws + WS_QQP);
  float*          attnT  = (float*)(ws + WS_ATTN);
  float*          outbuf = (float*)(ws + WS_OUT);
  float*          bnp    = (float*)(ws + WS_BN);

  pad_kernel    <<<25088, 256, 0, stream>>>(cen, cenbf);
  prep_kernel   <<<2304, 256, 0, stream>>>(sumw, kw, vw, Wb);
  qproj_kernel  <<<dim3(36, 8), 256, 0, stream>>>(cen, qw, qbf);
  conv_kv_mfma  <<<dim3(36, 1, 32), 512, 0, stream>>>(cenbf, Wb, KV);
  scores_mfma   <<<dim3(18, 4, 8), 256, 0, stream>>>(KV, qbf, spart, kkp, qqp);
  softmax_kernel<<<32, 256, 0, stream>>>(spart, kkp, qqp, attnT);
  pv_kernel     <<<dim3(9, 4, 8), 256, 0, stream>>>(KV, attnT, outbuf);
  outconv_kernel<<<dim3(36, 8), 256, 0, stream>>>(outbuf, ow, (float*)d_out);
  bnstats_kernel<<<dim3(64, 4), 256, 0, stream>>>((const float*)d_out, bnp);
  bnapply_kernel<<<4608, 256, 0, stream>>>((float*)d_out, bnp, gamma, beta);
}

// Round 8
// 427.695 us; speedup vs baseline: 2.4152x; 1.0332x over previous
//
#include <hip/hip_runtime.h>
#include <hip/hip_bf16.h>

// ---------------- sizes ----------------
// B=8, C=64, H=W=96, S=9216, NH=4 (dil=1,2,4,8), NL=8, hid=16
// KV rows per (i,b): 256 (0..127 = K via k_w, 128..255 = V via v_w)

// ---------------- workspace layout (bytes) ----------------
#define WS_CEN    0UL           // bf16 [8][64][112][112]     = 12,845,056
#define WS_SPART  12845056UL    // f32 [576][2048]            =  4,718,592
#define WS_W      25690112UL    // bf16 [4][18][256][32]      =  1,179,648 (frag-ready)
#define WS_Q      28049408UL    // bf16 [8][64][9216]         =  9,437,184 (row = o*4+i)
#define WS_KV     46923776UL    // bf16 [4][8][256][9216]     = 150,994,944
#define WS_KKP    197918720UL   // f32 [576][128]             =    294,912
#define WS_QQP    198213632UL   // f32 [576][16]              =     36,864
#define WS_ATTN   198250496UL   // f32 [32][128][16]          =    262,144
#define WS_AB     198512640UL   // bf16 [8][16][64][32]       =    524,288 (folded ow@attn, frag-ready)
#define WS_BNP    217387008UL   // f32 [576][128] per-block BN partials
#define WS_BNF    217681920UL   // f32 [128] combined sums

typedef __attribute__((ext_vector_type(8))) short short8;
typedef __attribute__((ext_vector_type(4))) float f32x4;

__device__ __forceinline__ float bflo(unsigned int u){ return __uint_as_float(u<<16); }
__device__ __forceinline__ float bfhi(unsigned int u){ return __uint_as_float(u & 0xffff0000u); }
__device__ __forceinline__ unsigned short f2bf(float f){
  unsigned int u = __float_as_uint(f);
  return (unsigned short)((u + 0x7fffu + ((u>>16)&1u)) >> 16);
}
__device__ __forceinline__ unsigned short fbits(float f){
  __hip_bfloat16 h = __float2bfloat16(f);
  return __builtin_bit_cast(unsigned short, h);
}

// ---- pad: cen [8,64,96,96] f32 -> cenbf [8,64,112,112] bf16 (8-halo zeros)
__global__ __launch_bounds__(256) void pad_kernel(const float* __restrict__ cen, unsigned short* __restrict__ cenbf){
  int idx = blockIdx.x*256 + threadIdx.x;  // exactly 6,422,528 threads
  int px = idx % 112; int t = idx / 112; int py = t % 112; int bc = t / 112;
  int y = py - 8, x = px - 8;
  float v = 0.f;
  if (y >= 0 && y < 96 && x >= 0 && x < 96) v = cen[(size_t)bc*9216 + y*96 + x];
  cenbf[idx] = fbits(v);
}

// ---- prep: build conv weights in bf16, fragment-ready layout
// Wb[((i*18 + kc)*256 + o)*32 + k'] where k = t*64 + c, kc=k>>5, k'=k&31
__global__ __launch_bounds__(256) void prep_kernel(const float* __restrict__ sumw,
    const float* __restrict__ kw, const float* __restrict__ vw, unsigned short* __restrict__ Wb){
  int idx = blockIdx.x*256 + threadIdx.x;  // exactly 589,824
  int o = idx & 255; int r = idx >> 8; int c = r & 63; r >>= 6; int t = r % 9; int i = r / 9;
  float l0 = sumw[(i*64 + c)*2 + 0], l1 = sumw[(i*64 + c)*2 + 1];
  float m = fmaxf(l0, l1);
  float e0 = expf(l0 - m), e1 = expf(l1 - m);
  float inv = 1.f/(e0 + e1);
  float sw0 = e0*inv, sw1 = e1*inv;
  const float* wsrc = (o < 128) ? (kw + ((size_t)i*128 + o)*512 + c)
                                : (vw + ((size_t)i*128 + (o-128))*512 + c);
  float A = 0.f;
  #pragma unroll
  for (int j = 0; j < 8; ++j) A += wsrc[j*64];
  float val;
  if (t == 4) {
    val = A;  // center tap: all mixed kernels have weight 1 at center (sw0+sw1=1)
  } else {
    const int tmap[9] = {0,1,2,7,0,3,6,5,4};
    int j = tmap[t];
    val = -(wsrc[j*64]*sw0 + A*sw1*0.125f);
  }
  int k = t*64 + c;
  Wb[(((size_t)i*18 + (k>>5))*256 + o)*32 + (k&31)] = f2bf(val);
}

// ---- Q projection: read cen ONCE, compute all 4 shifts x 16 rows -> Q bf16
__global__ __launch_bounds__(256) void qproj_kernel(const float* __restrict__ cen,
    const float* __restrict__ qw, unsigned short* __restrict__ qbf){
  __shared__ float WT[64][64];  // [c][row]
  int tid = threadIdx.x;
  int st = blockIdx.x, b = blockIdx.y;
  #pragma unroll
  for (int e = 0; e < 16; ++e) {
    int f = e*256 + tid; int c = f >> 6, row = f & 63;
    int i = row & 3, o = row >> 2;
    WT[c][row] = qw[(size_t)i*1024 + o*64 + c];
  }
  __syncthreads();
  int s = st*256 + tid;
  float acc[64];
  #pragma unroll
  for (int r = 0; r < 64; ++r) acc[r] = 0.f;
  const float* cb = cen + (size_t)b*64*9216 + s;
  for (int c = 0; c < 64; ++c) {
    float xv = cb[(size_t)c*9216];
    #pragma unroll
    for (int r4 = 0; r4 < 16; ++r4) {
      float4 w = *(const float4*)&WT[c][r4*4];
      acc[r4*4+0] = fmaf(w.x, xv, acc[r4*4+0]);
      acc[r4*4+1] = fmaf(w.y, xv, acc[r4*4+1]);
      acc[r4*4+2] = fmaf(w.z, xv, acc[r4*4+2]);
      acc[r4*4+3] = fmaf(w.w, xv, acc[r4*4+3]);
    }
  }
  unsigned short* qb = qbf + (size_t)b*64*9216 + s;
  #pragma unroll
  for (int r = 0; r < 64; ++r) qb[(size_t)r*9216] = fbits(acc[r]);
}

// ---- conv K/V via MFMA: 128x128 tile, 4 waves (2x2), 3 blocks/CU so barrier
// stalls of one block overlap another block's compute (m97-structure).
// acc[4][4]=64 AGPR; R3's proven conflict-free staging map at 128 rows.
__global__ __launch_bounds__(256, 3) void conv_kv_mfma(const unsigned short* __restrict__ cenbf,
    const unsigned short* __restrict__ Wb, unsigned short* __restrict__ KV){
  __shared__ char Xs[2][128*72];
  const int tid = threadIdx.x;
  const int st = blockIdx.x, oc = blockIdx.y, ib = blockIdx.z;
  const int i = ib >> 3, b = ib & 7;
  const int dil = 1 << i;
  const int s0 = st*128;
  const int wave = tid >> 6, lane = tid & 63;
  const int wm = wave >> 1, wn = wave & 1;
  const int l15 = lane & 15, l4 = lane >> 4;
  const int s_idx = tid & 127;
  const int khalf = tid >> 7;
  const int s = s0 + s_idx;
  const int y = s / 96, x = s - y*96;
  const unsigned short* cb = cenbf + (size_t)b*802816 + (size_t)(y+8)*112 + (x+8);

  f32x4 acc[4][4];
  #pragma unroll
  for (int mf = 0; mf < 4; ++mf)
    #pragma unroll
    for (int nf = 0; nf < 4; ++nf)
      acc[mf][nf] = (f32x4){0.f, 0.f, 0.f, 0.f};

  const unsigned short* Wi = Wb + (size_t)i*18*8192;
  const unsigned short* apb = Wi + (size_t)(oc*128 + wm*64 + l15)*32 + l4*8;

  unsigned short vs[16];
  auto gather = [&](int kn){
    int t = kn >> 1;
    int cbase = (kn & 1)*32 + khalf*16;
    int dy = (t/3 - 1)*dil, dx = (t - (t/3)*3 - 1)*dil;
    const unsigned short* p = cb + (size_t)cbase*12544 + (dy*112 + dx);
    #pragma unroll
    for (int j = 0; j < 16; ++j) vs[j] = p[(size_t)j*12544];
  };

  gather(0);
  int buf = 0;
  for (int kc = 0; kc < 18; ++kc) {
    short8 a[4];
    const unsigned short* ap = apb + (size_t)kc*8192;
    #pragma unroll
    for (int mf = 0; mf < 4; ++mf) a[mf] = *(const short8*)(ap + mf*512);
    asm volatile("" ::: "memory");
    char* wp = Xs[buf] + s_idx*72 + khalf*32;
    #pragma unroll
    for (int w = 0; w < 4; ++w) {
      unsigned int p0 = (unsigned int)vs[4*w+0] | ((unsigned int)vs[4*w+1] << 16);
      unsigned int p1 = (unsigned int)vs[4*w+2] | ((unsigned int)vs[4*w+3] << 16);
      *(uint2*)(wp + w*8) = make_uint2(p0, p1);
    }
    if (kc < 17) gather(kc + 1);
    asm volatile("s_waitcnt lgkmcnt(0)" ::: "memory");
    __builtin_amdgcn_s_barrier();
    asm volatile("" ::: "memory");
    short8 bfr[4];
    #pragma unroll
    for (int nf = 0; nf < 4; ++nf) {
      const char* rp = Xs[buf] + (wn*64 + nf*16 + l15)*72 + l4*16;
      uint2 lo = *(const uint2*)rp;
      uint2 hi = *(const uint2*)(rp + 8);
      uint4 tb = make_uint4(lo.x, lo.y, hi.x, hi.y);
      bfr[nf] = *(short8*)&tb;
    }
    #pragma unroll
    for (int mf = 0; mf < 4; ++mf)
      #pragma unroll
      for (int nf = 0; nf < 4; ++nf)
        acc[mf][nf] = __builtin_amdgcn_mfma_f32_16x16x32_bf16(a[mf], bfr[nf], acc[mf][nf], 0, 0, 0);
    buf ^= 1;
  }

  #pragma unroll
  for (int mf = 0; mf < 4; ++mf) {
    #pragma unroll
    for (int nf = 0; nf < 4; ++nf) {
      int scol = s0 + wn*64 + nf*16 + l15;
      int obase = oc*128 + wm*64 + mf*16 + l4*4;
      #pragma unroll
      for (int r = 0; r < 4; ++r)
        KV[((size_t)ib*256 + obase + r)*9216 + scol] = fbits(acc[mf][nf][r]);
    }
  }
}

// ---- scores via MFMA (unchanged from R7)
__global__ __launch_bounds__(256) void scores_mfma(const unsigned short* __restrict__ KV,
    const unsigned short* __restrict__ qbf, float* __restrict__ spart,
    float* __restrict__ kkpart, float* __restrict__ qqpart){
  __shared__ float red[4][2192];
  const int tid = threadIdx.x;
  const int chunk = blockIdx.x, hh = blockIdx.y, b = blockIdx.z;
  const int wave = tid >> 6, lane = tid & 63;
  const int l15 = lane & 15, l4 = lane >> 4;
  const int sbase = chunk*512 + wave*128;

  const unsigned short* qp = qbf + ((size_t)(b*64 + hh*16 + l15))*9216 + sbase + l4*8;
  const unsigned short* kp = KV + ((size_t)(((l15&3)*8 + b)*256 + hh*32 + (l15>>2)))*9216 + sbase + l4*8;

  f32x4 sacc[8], kkacc[8], qqacc;
  #pragma unroll
  for (int nf = 0; nf < 8; ++nf) { sacc[nf] = (f32x4){0,0,0,0}; kkacc[nf] = (f32x4){0,0,0,0}; }
  qqacc = (f32x4){0,0,0,0};

  #pragma unroll
  for (int sl = 0; sl < 4; ++sl) {
    short8 qf = *(const short8*)(qp + sl*32);
    short8 kf[8];
    #pragma unroll
    for (int nf = 0; nf < 8; ++nf) kf[nf] = *(const short8*)(kp + (size_t)nf*36864 + sl*32);
    qqacc = __builtin_amdgcn_mfma_f32_16x16x32_bf16(qf, qf, qqacc, 0, 0, 0);
    #pragma unroll
    for (int nf = 0; nf < 8; ++nf) {
      sacc[nf]  = __builtin_amdgcn_mfma_f32_16x16x32_bf16(qf, kf[nf], sacc[nf], 0, 0, 0);
      kkacc[nf] = __builtin_amdgcn_mfma_f32_16x16x32_bf16(kf[nf], kf[nf], kkacc[nf], 0, 0, 0);
    }
  }
  float* rw = red[wave];
  #pragma unroll
  for (int nf = 0; nf < 8; ++nf)
    #pragma unroll
    for (int r = 0; r < 4; ++r)
      rw[(l4*4 + r)*128 + nf*16 + l15] = sacc[nf][r];
  if ((l15 >> 2) == l4) {
    int r = l15 & 3;
    #pragma unroll
    for (int nf = 0; nf < 8; ++nf) rw[2048 + nf*16 + l15] = kkacc[nf][r];
    rw[2176 + l15] = qqacc[r];
  }
  __syncthreads();
  int pb = (b*4 + hh)*18 + chunk;
  for (int t = tid; t < 2192; t += 256) {
    float v = red[0][t] + red[1][t] + red[2][t] + red[3][t];
    if (t < 2048)       spart[(size_t)pb*2048 + t] = v;
    else if (t < 2176)  kkpart[(size_t)pb*128 + (t - 2048)] = v;
    else                qqpart[(size_t)pb*16 + (t - 2176)] = v;
  }
}

// ---- softmax (unchanged from R7)
__global__ __launch_bounds__(256) void softmax_kernel(const float* __restrict__ spart,
    const float* __restrict__ kkpart, const float* __restrict__ qqpart, float* __restrict__ attnT){
  const int pb = blockIdx.x, tid = threadIdx.x;
  const int qr = tid >> 4, g = tid & 15;
  __shared__ float kkl[128];
  __shared__ float qql[16];
  __shared__ float red[8];
  __shared__ float stats[2];
  float sv[8] = {0,0,0,0,0,0,0,0};
  for (int ch = 0; ch < 18; ++ch) {
    const float* p = spart + ((size_t)(pb*18 + ch))*2048 + qr*128 + g*8;
    #pragma unroll
    for (int e = 0; e < 8; ++e) sv[e] += p[e];
  }
  if (tid < 128) { float ssum = 0.f; for (int ch = 0; ch < 18; ++ch) ssum += kkpart[(size_t)(pb*18+ch)*128 + tid]; kkl[tid] = ssum; }
  if (tid < 16)  { float ssum = 0.f; for (int ch = 0; ch < 18; ++ch) ssum += qqpart[(size_t)(pb*18+ch)*16 + tid]; qql[tid] = ssum; }
  __syncthreads();
  float qn = fmaxf(sqrtf(qql[qr]), 1e-12f);
  float lsum = 0.f, lsq = 0.f;
  #pragma unroll
  for (int e = 0; e < 8; ++e) {
    float kn = fmaxf(sqrtf(kkl[g*8+e]), 1e-12f);
    float v = sv[e] / (qn * kn * 96.0f);
    sv[e] = v; lsum += v; lsq += v*v;
  }
  #pragma unroll
  for (int m = 1; m <= 32; m <<= 1) { lsum += __shfl_xor(lsum, m); lsq += __shfl_xor(lsq, m); }
  if ((tid & 63) == 0) { red[tid >> 6] = lsum; red[4 + (tid >> 6)] = lsq; }
  __syncthreads();
  if (tid == 0) {
    float ts = red[0]+red[1]+red[2]+red[3];
    float tq = red[4]+red[5]+red[6]+red[7];
    float mean = ts / 2048.0f;
    float var = tq / 2048.0f - mean*mean;
    stats[0] = mean; stats[1] = rsqrtf(var + 1e-5f);
  }
  __syncthreads();
  float mean = stats[0], inv = stats[1];
  float mx = -1e30f;
  #pragma unroll
  for (int e = 0; e < 8; ++e) { sv[e] = (sv[e] - mean) * inv; mx = fmaxf(mx, sv[e]); }
  #pragma unroll
  for (int m = 1; m <= 8; m <<= 1) mx = fmaxf(mx, __shfl_xor(mx, m));
  float es = 0.f;
  #pragma unroll
  for (int e = 0; e < 8; ++e) { sv[e] = expf(sv[e] - mx); es += sv[e]; }
  #pragma unroll
  for (int m = 1; m <= 8; m <<= 1) es += __shfl_xor(es, m);
  float rinv = 1.0f / es;
  #pragma unroll
  for (int e = 0; e < 8; ++e) attnT[(size_t)pb*2048 + (g*8+e)*16 + qr] = sv[e] * rinv;
}

// ---- attn fold: M[b][r][o2] = sum_qr ow[o2][hh*16+qr] * attn[b,hh][kr][qr]
// r-order: r = (kr&3)*128 + hh*32 + (kr>>2) so V rows within a 32-chunk have
// uniform stride; stored frag-ready Ab[((b*16 + r>>5)*64 + o2)*32 + (r&31)].
__global__ __launch_bounds__(256) void attnfold_kernel(const float* __restrict__ attnT,
    const float* __restrict__ ow, unsigned short* __restrict__ Ab){
  int idx = blockIdx.x*256 + threadIdx.x;  // exactly 262,144
  int kr = idx & 127, hh = (idx >> 7) & 3, o2 = (idx >> 9) & 63, b = idx >> 15;
  const float* ap = attnT + ((size_t)(b*4 + hh))*2048 + kr*16;
  const float* wp = ow + o2*64 + hh*16;
  float acc = 0.f;
  #pragma unroll
  for (int qr = 0; qr < 16; ++qr) acc += wp[qr] * ap[qr];
  int rc = (kr & 3)*4 + hh, ch = kr >> 2;
  Ab[(((size_t)b*16 + rc)*64 + o2)*32 + ch] = fbits(acc);
}

// ---- ygemm: y[b][o2][s] = M[b] @ V[b]  ([64 x 512] @ [512 x 9216]), replaces
// pv + outconv. BN partials computed in epilogue (non-atomic per block).
// 256 thr, 4 waves (2 wm x 2 wn), tile O=64 x S=128, K=512 in 16 chunks of 32.
__global__ __launch_bounds__(256, 3) void ygemm_kernel(const unsigned short* __restrict__ KV,
    const unsigned short* __restrict__ Ab, float* __restrict__ dout, float* __restrict__ bnpart){
  __shared__ char Xs[2][128*72];
  __shared__ float bns[4][32], bnq[4][32];
  const int tid = threadIdx.x;
  const int st = blockIdx.x, b = blockIdx.y;
  const int wave = tid >> 6, lane = tid & 63;
  const int wm = wave >> 1, wn = wave & 1;
  const int l15 = lane & 15, l4 = lane >> 4;
  const int s_idx = tid & 127, khalf = tid >> 7;
  const int s0 = st*128;

  f32x4 acc[2][4];
  #pragma unroll
  for (int mf = 0; mf < 2; ++mf)
    #pragma unroll
    for (int nf = 0; nf < 4; ++nf)
      acc[mf][nf] = (f32x4){0.f, 0.f, 0.f, 0.f};

  const unsigned short* Abb = Ab + ((size_t)b*16*64)*32 + (size_t)(wm*32 + l15)*32 + l4*8;

  unsigned short vs[16];
  auto vgather = [&](int kn){
    // chunk kn: rows j = khalf*16..+15 of V chunk (ii = kn>>2, hh = kn&3)
    int vr = (((kn >> 2)*8 + b)*256 + 128 + (kn & 3)*32) + khalf*16;
    const unsigned short* p = KV + (size_t)vr*9216 + s0 + s_idx;
    #pragma unroll
    for (int j = 0; j < 16; ++j) vs[j] = p[(size_t)j*9216];
  };

  vgather(0);
  int buf = 0;
  for (int kc = 0; kc < 16; ++kc) {
    short8 a[2];
    #pragma unroll
    for (int mf = 0; mf < 2; ++mf) a[mf] = *(const short8*)(Abb + (size_t)kc*2048 + mf*512);
    asm volatile("" ::: "memory");
    char* wp = Xs[buf] + s_idx*72 + khalf*32;
    #pragma unroll
    for (int w = 0; w < 4; ++w) {
      unsigned int p0 = (unsigned int)vs[4*w+0] | ((unsigned int)vs[4*w+1] << 16);
      unsigned int p1 = (unsigned int)vs[4*w+2] | ((unsigned int)vs[4*w+3] << 16);
      *(uint2*)(wp + w*8) = make_uint2(p0, p1);
    }
    if (kc < 15) vgather(kc + 1);
    asm volatile("s_waitcnt lgkmcnt(0)" ::: "memory");
    __builtin_amdgcn_s_barrier();
    asm volatile("" ::: "memory");
    short8 bfr[4];
    #pragma unroll
    for (int nf = 0; nf < 4; ++nf) {
      const char* rp = Xs[buf] + (wn*64 + nf*16 + l15)*72 + l4*16;
      uint2 lo = *(const uint2*)rp;
      uint2 hi = *(const uint2*)(rp + 8);
      uint4 tb = make_uint4(lo.x, lo.y, hi.x, hi.y);
      bfr[nf] = *(short8*)&tb;
    }
    #pragma unroll
    for (int mf = 0; mf < 2; ++mf)
      #pragma unroll
      for (int nf = 0; nf < 4; ++nf)
        acc[mf][nf] = __builtin_amdgcn_mfma_f32_16x16x32_bf16(a[mf], bfr[nf], acc[mf][nf], 0, 0, 0);
    buf ^= 1;
  }

  // epilogue: write y (f32) + BN partial sums
  #pragma unroll
  for (int mf = 0; mf < 2; ++mf) {
    #pragma unroll
    for (int rr = 0; rr < 4; ++rr) {
      int o2 = wm*32 + mf*16 + l4*4 + rr;
      float vsum = 0.f, vsq = 0.f;
      #pragma unroll
      for (int nf = 0; nf < 4; ++nf) {
        float v = acc[mf][nf][rr];
        vsum += v; vsq += v*v;
        dout[((size_t)(b*64 + o2))*9216 + s0 + wn*64 + nf*16 + l15] = v;
      }
      #pragma unroll
      for (int m = 1; m <= 8; m <<= 1) { vsum += __shfl_xor(vsum, m); vsq += __shfl_xor(vsq, m); }
      if (l15 == 0) { bns[wave][mf*16 + l4*4 + rr] = vsum; bnq[wave][mf*16 + l4*4 + rr] = vsq; }
    }
  }
  __syncthreads();
  if (tid < 64) {
    int wmq = tid >> 5, local = tid & 31;
    float s_ = bns[wmq*2][local] + bns[wmq*2+1][local];
    float q_ = bnq[wmq*2][local] + bnq[wmq*2+1][local];
    int bid = b*72 + st;
    bnpart[(size_t)bid*128 + tid] = s_;
    bnpart[(size_t)bid*128 + 64 + tid] = q_;
  }
}

// ---- combine BN partials: [576][128] -> [128] raw sums
__global__ __launch_bounds__(128) void bncombine_kernel(const float* __restrict__ bnpart, float* __restrict__ bnfin){
  int t = threadIdx.x;  // 128
  float a = 0.f;
  for (int blk = 0; blk < 576; ++blk) a += bnpart[(size_t)blk*128 + t];
  bnfin[t] = a;
}

// ---- BN apply + ReLU (in place on d_out), float4
__global__ __launch_bounds__(256) void bnapply_kernel(float* __restrict__ yb,
    const float* __restrict__ bnfin, const float* __restrict__ gamma, const float* __restrict__ beta){
  int gid = blockIdx.x*256 + threadIdx.x;  // exactly 1,179,648 float4s
  int o = (gid / 2304) & 63;
  float mean = bnfin[o] * (1.f/73728.f);
  float var = bnfin[64 + o] * (1.f/73728.f) - mean*mean;
  float inv = rsqrtf(var + 1e-5f);
  float g = gamma[o], be = beta[o];
  float4 v = ((const float4*)yb)[gid];
  v.x = fmaxf((v.x - mean)*inv*g + be, 0.f);
  v.y = fmaxf((v.y - mean)*inv*g + be, 0.f);
  v.z = fmaxf((v.z - mean)*inv*g + be, 0.f);
  v.w = fmaxf((v.w - mean)*inv*g + be, 0.f);
  ((float4*)yb)[gid] = v;
}

extern "C" void kernel_launch(void* const* d_in, const int* in_sizes, int n_in,
                              void* d_out, int out_size, void* d_ws, size_t ws_size,
                              hipStream_t stream) {
  const float* cen   = (const float*)d_in[0];
  const float* sumw  = (const float*)d_in[1];
  const float* qw    = (const float*)d_in[2];
  const float* kw    = (const float*)d_in[3];
  const float* vw    = (const float*)d_in[4];
  const float* ow    = (const float*)d_in[5];
  const float* gamma = (const float*)d_in[6];
  const float* beta  = (const float*)d_in[7];

  char* ws = (char*)d_ws;
  unsigned short* cenbf  = (unsigned short*)(ws + WS_CEN);
  float*          spart  = (float*)(ws + WS_SPART);
  unsigned short* Wb     = (unsigned short*)(ws + WS_W);
  unsigned short* qbf    = (unsigned short*)(ws + WS_Q);
  unsigned short* KV     = (unsigned short*)(ws + WS_KV);
  float*          kkp    = (float*)(ws + WS_KKP);
  float*          qqp    = (float*)(ws + WS_QQP);
  float*          attnT  = (float*)(ws + WS_ATTN);
  unsigned short* Ab     = (unsigned short*)(ws + WS_AB);
  float*          bnp    = (float*)(ws + WS_BNP);
  float*          bnf    = (float*)(ws + WS_BNF);

  pad_kernel     <<<25088, 256, 0, stream>>>(cen, cenbf);
  prep_kernel    <<<2304, 256, 0, stream>>>(sumw, kw, vw, Wb);
  qproj_kernel   <<<dim3(36, 8), 256, 0, stream>>>(cen, qw, qbf);
  conv_kv_mfma   <<<dim3(72, 2, 32), 256, 0, stream>>>(cenbf, Wb, KV);
  scores_mfma    <<<dim3(18, 4, 8), 256, 0, stream>>>(KV, qbf, spart, kkp, qqp);
  softmax_kernel <<<32, 256, 0, stream>>>(spart, kkp, qqp, attnT);
  attnfold_kernel<<<1024, 256, 0, stream>>>(attnT, ow, Ab);
  ygemm_kernel   <<<dim3(72, 8), 256, 0, stream>>>(KV, Ab, (float*)d_out, bnp);
  bncombine_kernel<<<1, 128, 0, stream>>>(bnp, bnf);
  bnapply_kernel <<<4608, 256, 0, stream>>>((float*)d_out, bnf, gamma, beta);
}

// Round 9
// 414.973 us; speedup vs baseline: 2.4893x; 1.0307x over previous
//
#include <hip/hip_runtime.h>
#include <hip/hip_bf16.h>

// ---------------- sizes ----------------
// B=8, C=64, H=W=96, S=9216, NH=4 (dil=1,2,4,8), NL=8, hid=16
// KV rows per (i,b): 256 (0..127 = K via k_w, 128..255 = V via v_w)
// conv GEMM per (i,b): [256 o] x [576 k = tap*64+c] x [9216 s]; BK=64 = 1 tap

// ---------------- workspace layout (bytes) ----------------
#define WS_CEN    0UL           // bf16 [8][64][112][112]     = 12,845,056
#define WS_CEN1   12845056UL    // bf16 same, shifted +1 elem = 12,845,056
#define WS_W      25690112UL    // bf16 [4][9][256][64]       =  1,179,648 (frag-ready)
#define WS_Q      28049408UL    // bf16 [8][64][9216]         =  9,437,184 (row = o*4+i)
#define WS_KV     46923776UL    // bf16 [4][8][256][9216]     = 150,994,944
#define WS_SPART  197918720UL   // f32 [576][2048]            =  4,718,592
#define WS_KKP    202637312UL   // f32 [576][128]             =    294,912
#define WS_QQP    202932224UL   // f32 [576][16]              =     36,864
#define WS_ATTN   202969088UL   // f32 [32][128][16]          =    262,144
#define WS_AB     203231232UL   // bf16 [8][16][64][32]       =    524,288 (folded ow@attn)
#define WS_BNP    203755520UL   // f32 [576][128] per-block BN partials
#define WS_BNF    204050432UL   // f32 [128] combined sums

typedef __attribute__((ext_vector_type(8))) short short8;
typedef __attribute__((ext_vector_type(4))) float f32x4;

__device__ __forceinline__ float bflo(unsigned int u){ return __uint_as_float(u<<16); }
__device__ __forceinline__ float bfhi(unsigned int u){ return __uint_as_float(u & 0xffff0000u); }
__device__ __forceinline__ unsigned short f2bf(float f){
  unsigned int u = __float_as_uint(f);
  return (unsigned short)((u + 0x7fffu + ((u>>16)&1u)) >> 16);
}
__device__ __forceinline__ unsigned short fbits(float f){
  __hip_bfloat16 h = __float2bfloat16(f);
  return __builtin_bit_cast(unsigned short, h);
}

// ---- pad: cen f32 -> cenbf bf16 [8,64,112,112] (8-halo) + cenbf1 shifted +1
__global__ __launch_bounds__(256) void pad_kernel(const float* __restrict__ cen,
    unsigned short* __restrict__ cenbf, unsigned short* __restrict__ cenbf1){
  int idx = blockIdx.x*256 + threadIdx.x;  // exactly 6,422,528 threads
  int px = idx % 112; int t = idx / 112; int py = t % 112; int bc = t / 112;
  int y = py - 8, x = px - 8;
  float v = 0.f;
  if (y >= 0 && y < 96 && x >= 0 && x < 96) v = cen[(size_t)bc*9216 + y*96 + x];
  unsigned short h = fbits(v);
  cenbf[idx] = h;
  if (idx > 0) cenbf1[idx-1] = h;   // cenbf1[e] = elem(e+1)
}

// ---- prep: conv weights bf16, frag-ready: Wb[((i*9 + t)*256 + o)*64 + c]
__global__ __launch_bounds__(256) void prep_kernel(const float* __restrict__ sumw,
    const float* __restrict__ kw, const float* __restrict__ vw, unsigned short* __restrict__ Wb){
  int idx = blockIdx.x*256 + threadIdx.x;  // exactly 589,824
  int o = idx & 255; int r = idx >> 8; int c = r & 63; r >>= 6; int t = r % 9; int i = r / 9;
  float l0 = sumw[(i*64 + c)*2 + 0], l1 = sumw[(i*64 + c)*2 + 1];
  float m = fmaxf(l0, l1);
  float e0 = expf(l0 - m), e1 = expf(l1 - m);
  float inv = 1.f/(e0 + e1);
  float sw0 = e0*inv, sw1 = e1*inv;
  const float* wsrc = (o < 128) ? (kw + ((size_t)i*128 + o)*512 + c)
                                : (vw + ((size_t)i*128 + (o-128))*512 + c);
  float A = 0.f;
  #pragma unroll
  for (int j = 0; j < 8; ++j) A += wsrc[j*64];
  float val;
  if (t == 4) {
    val = A;  // center tap: all mixed kernels weight 1 at center (sw0+sw1=1)
  } else {
    const int tmap[9] = {0,1,2,7,0,3,6,5,4};
    int j = tmap[t];
    val = -(wsrc[j*64]*sw0 + A*sw1*0.125f);
  }
  Wb[(((size_t)i*9 + t)*256 + o)*64 + c] = f2bf(val);
}

// ---- Q projection: read cen ONCE, all 4 shifts x 16 rows -> Q bf16
__global__ __launch_bounds__(256) void qproj_kernel(const float* __restrict__ cen,
    const float* __restrict__ qw, unsigned short* __restrict__ qbf){
  __shared__ float WT[64][64];  // [c][row]
  int tid = threadIdx.x;
  int st = blockIdx.x, b = blockIdx.y;
  #pragma unroll
  for (int e = 0; e < 16; ++e) {
    int f = e*256 + tid; int c = f >> 6, row = f & 63;
    int i = row & 3, o = row >> 2;
    WT[c][row] = qw[(size_t)i*1024 + o*64 + c];
  }
  __syncthreads();
  int s = st*256 + tid;
  float acc[64];
  #pragma unroll
  for (int r = 0; r < 64; ++r) acc[r] = 0.f;
  const float* cb = cen + (size_t)b*64*9216 + s;
  for (int c = 0; c < 64; ++c) {
    float xv = cb[(size_t)c*9216];
    #pragma unroll
    for (int r4 = 0; r4 < 16; ++r4) {
      float4 w = *(const float4*)&WT[c][r4*4];
      acc[r4*4+0] = fmaf(w.x, xv, acc[r4*4+0]);
      acc[r4*4+1] = fmaf(w.y, xv, acc[r4*4+1]);
      acc[r4*4+2] = fmaf(w.z, xv, acc[r4*4+2]);
      acc[r4*4+3] = fmaf(w.w, xv, acc[r4*4+3]);
    }
  }
  unsigned short* qb = qbf + (size_t)b*64*9216 + s;
  #pragma unroll
  for (int r = 0; r < 64; ++r) qb[(size_t)r*9216] = fbits(acc[r]);
}

// ---- conv K/V via MFMA: 256x256 tile, 8 waves (2x4), BK=64 = ONE TAP/chunk.
// 9 barriers, 64 MFMA/wave/chunk. Gather vectorized to 16 uint loads/thread
// (2 s x 16 c); odd-dx shifts use the +1-shifted image copy for alignment.
// Issue order (counted vmcnt): A(t) -> pack_t -> gather(t+1) -> lgkm-only
// barrier -> ds_read -> MFMA. Nothing drains vmcnt to 0.
__global__ __launch_bounds__(512, 2) void conv_kv_mfma(const unsigned short* __restrict__ cenbf,
    const unsigned short* __restrict__ cenbf1, const unsigned short* __restrict__ Wb,
    unsigned short* __restrict__ KV){
  __shared__ char Xs[2][256*136];   // [s][64 c x 2B + 8B pad]
  const int tid = threadIdx.x;
  const int st = blockIdx.x, ib = blockIdx.z;
  const int i = ib >> 3, b = ib & 7;
  const int dil = 1 << i;
  const int s0 = st*256;
  const int wave = tid >> 6, lane = tid & 63;
  const int wm = wave >> 2, wn = wave & 3;
  const int l15 = lane & 15, l4 = lane >> 4;
  // staging: thread covers s-pair (2 consecutive s) x 16 channels
  const int p = tid & 127, cg = tid >> 7;     // cg in 0..3
  const int sl = 2*p;
  const int s = s0 + sl;
  const int y = s / 96, x = s - y*96;         // pair never crosses a row (even start)
  const long ebase = (long)b*802816 + (long)(cg*16)*12544 + (long)(y+8)*112 + (x+8);

  f32x4 acc[8][4];
  #pragma unroll
  for (int mf = 0; mf < 8; ++mf)
    #pragma unroll
    for (int nf = 0; nf < 4; ++nf)
      acc[mf][nf] = (f32x4){0.f, 0.f, 0.f, 0.f};

  const unsigned short* Wi = Wb + (size_t)i*9*16384;
  const unsigned short* apb = Wi + (size_t)(wm*128 + l15)*64 + l4*8;

  unsigned int vs[16];
  auto gather = [&](int t){
    int dy = (t/3 - 1)*dil, dx = (t - (t/3)*3 - 1)*dil;
    long e0 = ebase + dy*112 + dx;
    const unsigned short* src = (dx & 1) ? (cenbf1 + (e0 - 1)) : (cenbf + e0);
    #pragma unroll
    for (int j = 0; j < 16; ++j) vs[j] = *(const unsigned int*)(src + (size_t)j*12544);
  };

  gather(0);   // prologue
  int buf = 0;
  for (int t = 0; t < 9; ++t) {
    // ---- 1. A fragments first (waiting for A never drains the prefetch)
    short8 a[8][2];
    const unsigned short* ap = apb + (size_t)t*16384;
    #pragma unroll
    for (int mf = 0; mf < 8; ++mf)
      #pragma unroll
      for (int ks = 0; ks < 2; ++ks)
        a[mf][ks] = *(const short8*)(ap + mf*1024 + ks*32);
    asm volatile("" ::: "memory");   // pin A-loads before pack/gather
    // ---- 2. pack gather_t (reg transpose pair->rows) & write LDS
    {
      unsigned int lo[8], hi[8];
      #pragma unroll
      for (int w = 0; w < 8; ++w) {
        lo[w] = (vs[2*w] & 0xffffu) | (vs[2*w+1] << 16);
        hi[w] = (vs[2*w] >> 16)    | (vs[2*w+1] & 0xffff0000u);
      }
      char* r0 = Xs[buf] + sl*136 + cg*32;
      char* r1 = r0 + 136;
      #pragma unroll
      for (int w = 0; w < 4; ++w) {
        *(uint2*)(r0 + w*8) = make_uint2(lo[2*w], lo[2*w+1]);
        *(uint2*)(r1 + w*8) = make_uint2(hi[2*w], hi[2*w+1]);
      }
    }
    // ---- 3. prefetch next tap's gather (register WAR on vs pins order)
    if (t < 8) gather(t + 1);
    // ---- 4. LDS-only drain + raw barrier (NO vmcnt drain)
    asm volatile("s_waitcnt lgkmcnt(0)" ::: "memory");
    __builtin_amdgcn_s_barrier();
    asm volatile("" ::: "memory");
    // ---- 5. B fragments from LDS (136B rows; quarter-wave conflict-free)
    short8 bfr[4][2];
    #pragma unroll
    for (int nf = 0; nf < 4; ++nf) {
      const char* rp = Xs[buf] + (wn*64 + nf*16 + l15)*136 + l4*16;
      #pragma unroll
      for (int ks = 0; ks < 2; ++ks) {
        uint2 lo2 = *(const uint2*)(rp + ks*64);
        uint2 hi2 = *(const uint2*)(rp + ks*64 + 8);
        uint4 tb = make_uint4(lo2.x, lo2.y, hi2.x, hi2.y);
        bfr[nf][ks] = *(short8*)&tb;
      }
    }
    // ---- 6. 64 MFMA (lgkm for B, vmcnt(16) for A)
    #pragma unroll
    for (int ks = 0; ks < 2; ++ks)
      #pragma unroll
      for (int mf = 0; mf < 8; ++mf)
        #pragma unroll
        for (int nf = 0; nf < 4; ++nf)
          acc[mf][nf] = __builtin_amdgcn_mfma_f32_16x16x32_bf16(a[mf][ks], bfr[nf][ks], acc[mf][nf], 0, 0, 0);
    buf ^= 1;
  }

  // ---- epilogue: C/D mapping row=(l>>4)*4+r, col=l&15
  #pragma unroll
  for (int mf = 0; mf < 8; ++mf) {
    #pragma unroll
    for (int nf = 0; nf < 4; ++nf) {
      int scol = s0 + wn*64 + nf*16 + l15;
      int obase = wm*128 + mf*16 + l4*4;
      #pragma unroll
      for (int r = 0; r < 4; ++r)
        KV[((size_t)ib*256 + obase + r)*9216 + scol] = fbits(acc[mf][nf][r]);
    }
  }
}

// ---- scores via MFMA (unchanged)
__global__ __launch_bounds__(256) void scores_mfma(const unsigned short* __restrict__ KV,
    const unsigned short* __restrict__ qbf, float* __restrict__ spart,
    float* __restrict__ kkpart, float* __restrict__ qqpart){
  __shared__ float red[4][2192];
  const int tid = threadIdx.x;
  const int chunk = blockIdx.x, hh = blockIdx.y, b = blockIdx.z;
  const int wave = tid >> 6, lane = tid & 63;
  const int l15 = lane & 15, l4 = lane >> 4;
  const int sbase = chunk*512 + wave*128;

  const unsigned short* qp = qbf + ((size_t)(b*64 + hh*16 + l15))*9216 + sbase + l4*8;
  const unsigned short* kp = KV + ((size_t)(((l15&3)*8 + b)*256 + hh*32 + (l15>>2)))*9216 + sbase + l4*8;

  f32x4 sacc[8], kkacc[8], qqacc;
  #pragma unroll
  for (int nf = 0; nf < 8; ++nf) { sacc[nf] = (f32x4){0,0,0,0}; kkacc[nf] = (f32x4){0,0,0,0}; }
  qqacc = (f32x4){0,0,0,0};

  #pragma unroll
  for (int sl = 0; sl < 4; ++sl) {
    short8 qf = *(const short8*)(qp + sl*32);
    short8 kf[8];
    #pragma unroll
    for (int nf = 0; nf < 8; ++nf) kf[nf] = *(const short8*)(kp + (size_t)nf*36864 + sl*32);
    qqacc = __builtin_amdgcn_mfma_f32_16x16x32_bf16(qf, qf, qqacc, 0, 0, 0);
    #pragma unroll
    for (int nf = 0; nf < 8; ++nf) {
      sacc[nf]  = __builtin_amdgcn_mfma_f32_16x16x32_bf16(qf, kf[nf], sacc[nf], 0, 0, 0);
      kkacc[nf] = __builtin_amdgcn_mfma_f32_16x16x32_bf16(kf[nf], kf[nf], kkacc[nf], 0, 0, 0);
    }
  }
  float* rw = red[wave];
  #pragma unroll
  for (int nf = 0; nf < 8; ++nf)
    #pragma unroll
    for (int r = 0; r < 4; ++r)
      rw[(l4*4 + r)*128 + nf*16 + l15] = sacc[nf][r];
  if ((l15 >> 2) == l4) {
    int r = l15 & 3;
    #pragma unroll
    for (int nf = 0; nf < 8; ++nf) rw[2048 + nf*16 + l15] = kkacc[nf][r];
    rw[2176 + l15] = qqacc[r];
  }
  __syncthreads();
  int pb = (b*4 + hh)*18 + chunk;
  for (int t = tid; t < 2192; t += 256) {
    float v = red[0][t] + red[1][t] + red[2][t] + red[3][t];
    if (t < 2048)       spart[(size_t)pb*2048 + t] = v;
    else if (t < 2176)  kkpart[(size_t)pb*128 + (t - 2048)] = v;
    else                qqpart[(size_t)pb*16 + (t - 2176)] = v;
  }
}

// ---- softmax (unchanged)
__global__ __launch_bounds__(256) void softmax_kernel(const float* __restrict__ spart,
    const float* __restrict__ kkpart, const float* __restrict__ qqpart, float* __restrict__ attnT){
  const int pb = blockIdx.x, tid = threadIdx.x;
  const int qr = tid >> 4, g = tid & 15;
  __shared__ float kkl[128];
  __shared__ float qql[16];
  __shared__ float red[8];
  __shared__ float stats[2];
  float sv[8] = {0,0,0,0,0,0,0,0};
  for (int ch = 0; ch < 18; ++ch) {
    const float* p = spart + ((size_t)(pb*18 + ch))*2048 + qr*128 + g*8;
    #pragma unroll
    for (int e = 0; e < 8; ++e) sv[e] += p[e];
  }
  if (tid < 128) { float ssum = 0.f; for (int ch = 0; ch < 18; ++ch) ssum += kkpart[(size_t)(pb*18+ch)*128 + tid]; kkl[tid] = ssum; }
  if (tid < 16)  { float ssum = 0.f; for (int ch = 0; ch < 18; ++ch) ssum += qqpart[(size_t)(pb*18+ch)*16 + tid]; qql[tid] = ssum; }
  __syncthreads();
  float qn = fmaxf(sqrtf(qql[qr]), 1e-12f);
  float lsum = 0.f, lsq = 0.f;
  #pragma unroll
  for (int e = 0; e < 8; ++e) {
    float kn = fmaxf(sqrtf(kkl[g*8+e]), 1e-12f);
    float v = sv[e] / (qn * kn * 96.0f);
    sv[e] = v; lsum += v; lsq += v*v;
  }
  #pragma unroll
  for (int m = 1; m <= 32; m <<= 1) { lsum += __shfl_xor(lsum, m); lsq += __shfl_xor(lsq, m); }
  if ((tid & 63) == 0) { red[tid >> 6] = lsum; red[4 + (tid >> 6)] = lsq; }
  __syncthreads();
  if (tid == 0) {
    float ts = red[0]+red[1]+red[2]+red[3];
    float tq = red[4]+red[5]+red[6]+red[7];
    float mean = ts / 2048.0f;
    float var = tq / 2048.0f - mean*mean;
    stats[0] = mean; stats[1] = rsqrtf(var + 1e-5f);
  }
  __syncthreads();
  float mean = stats[0], inv = stats[1];
  float mx = -1e30f;
  #pragma unroll
  for (int e = 0; e < 8; ++e) { sv[e] = (sv[e] - mean) * inv; mx = fmaxf(mx, sv[e]); }
  #pragma unroll
  for (int m = 1; m <= 8; m <<= 1) mx = fmaxf(mx, __shfl_xor(mx, m));
  float es = 0.f;
  #pragma unroll
  for (int e = 0; e < 8; ++e) { sv[e] = expf(sv[e] - mx); es += sv[e]; }
  #pragma unroll
  for (int m = 1; m <= 8; m <<= 1) es += __shfl_xor(es, m);
  float rinv = 1.0f / es;
  #pragma unroll
  for (int e = 0; e < 8; ++e) attnT[(size_t)pb*2048 + (g*8+e)*16 + qr] = sv[e] * rinv;
}

// ---- attn fold: M[b][r][o2] = sum_qr ow[o2][hh*16+qr] * attn[b,hh][kr][qr]
__global__ __launch_bounds__(256) void attnfold_kernel(const float* __restrict__ attnT,
    const float* __restrict__ ow, unsigned short* __restrict__ Ab){
  int idx = blockIdx.x*256 + threadIdx.x;  // exactly 262,144
  int kr = idx & 127, hh = (idx >> 7) & 3, o2 = (idx >> 9) & 63, b = idx >> 15;
  const float* ap = attnT + ((size_t)(b*4 + hh))*2048 + kr*16;
  const float* wp = ow + o2*64 + hh*16;
  float acc = 0.f;
  #pragma unroll
  for (int qr = 0; qr < 16; ++qr) acc += wp[qr] * ap[qr];
  int rc = (kr & 3)*4 + hh, ch = kr >> 2;
  Ab[(((size_t)b*16 + rc)*64 + o2)*32 + ch] = fbits(acc);
}

// ---- ygemm: y[b][o2][s] = M[b] @ V[b] ([64 x 512] @ [512 x 9216]) + BN partials
__global__ __launch_bounds__(256, 3) void ygemm_kernel(const unsigned short* __restrict__ KV,
    const unsigned short* __restrict__ Ab, float* __restrict__ dout, float* __restrict__ bnpart){
  __shared__ char Xs[2][128*72];
  __shared__ float bns[4][32], bnq[4][32];
  const int tid = threadIdx.x;
  const int st = blockIdx.x, b = blockIdx.y;
  const int wave = tid >> 6, lane = tid & 63;
  const int wm = wave >> 1, wn = wave & 1;
  const int l15 = lane & 15, l4 = lane >> 4;
  const int s_idx = tid & 127, khalf = tid >> 7;
  const int s0 = st*128;

  f32x4 acc[2][4];
  #pragma unroll
  for (int mf = 0; mf < 2; ++mf)
    #pragma unroll
    for (int nf = 0; nf < 4; ++nf)
      acc[mf][nf] = (f32x4){0.f, 0.f, 0.f, 0.f};

  const unsigned short* Abb = Ab + ((size_t)b*16*64)*32 + (size_t)(wm*32 + l15)*32 + l4*8;

  unsigned short vs[16];
  auto vgather = [&](int kn){
    int vr = (((kn >> 2)*8 + b)*256 + 128 + (kn & 3)*32) + khalf*16;
    const unsigned short* p = KV + (size_t)vr*9216 + s0 + s_idx;
    #pragma unroll
    for (int j = 0; j < 16; ++j) vs[j] = p[(size_t)j*9216];
  };

  vgather(0);
  int buf = 0;
  for (int kc = 0; kc < 16; ++kc) {
    short8 a[2];
    #pragma unroll
    for (int mf = 0; mf < 2; ++mf) a[mf] = *(const short8*)(Abb + (size_t)kc*2048 + mf*512);
    asm volatile("" ::: "memory");
    char* wp = Xs[buf] + s_idx*72 + khalf*32;
    #pragma unroll
    for (int w = 0; w < 4; ++w) {
      unsigned int p0 = (unsigned int)vs[4*w+0] | ((unsigned int)vs[4*w+1] << 16);
      unsigned int p1 = (unsigned int)vs[4*w+2] | ((unsigned int)vs[4*w+3] << 16);
      *(uint2*)(wp + w*8) = make_uint2(p0, p1);
    }
    if (kc < 15) vgather(kc + 1);
    asm volatile("s_waitcnt lgkmcnt(0)" ::: "memory");
    __builtin_amdgcn_s_barrier();
    asm volatile("" ::: "memory");
    short8 bfr[4];
    #pragma unroll
    for (int nf = 0; nf < 4; ++nf) {
      const char* rp = Xs[buf] + (wn*64 + nf*16 + l15)*72 + l4*16;
      uint2 lo = *(const uint2*)rp;
      uint2 hi = *(const uint2*)(rp + 8);
      uint4 tb = make_uint4(lo.x, lo.y, hi.x, hi.y);
      bfr[nf] = *(short8*)&tb;
    }
    #pragma unroll
    for (int mf = 0; mf < 2; ++mf)
      #pragma unroll
      for (int nf = 0; nf < 4; ++nf)
        acc[mf][nf] = __builtin_amdgcn_mfma_f32_16x16x32_bf16(a[mf], bfr[nf], acc[mf][nf], 0, 0, 0);
    buf ^= 1;
  }

  #pragma unroll
  for (int mf = 0; mf < 2; ++mf) {
    #pragma unroll
    for (int rr = 0; rr < 4; ++rr) {
      int o2 = wm*32 + mf*16 + l4*4 + rr;
      float vsum = 0.f, vsq = 0.f;
      #pragma unroll
      for (int nf = 0; nf < 4; ++nf) {
        float v = acc[mf][nf][rr];
        vsum += v; vsq += v*v;
        dout[((size_t)(b*64 + o2))*9216 + s0 + wn*64 + nf*16 + l15] = v;
      }
      #pragma unroll
      for (int m = 1; m <= 8; m <<= 1) { vsum += __shfl_xor(vsum, m); vsq += __shfl_xor(vsq, m); }
      if (l15 == 0) { bns[wave][mf*16 + l4*4 + rr] = vsum; bnq[wave][mf*16 + l4*4 + rr] = vsq; }
    }
  }
  __syncthreads();
  if (tid < 64) {
    int wmq = tid >> 5, local = tid & 31;
    float s_ = bns[wmq*2][local] + bns[wmq*2+1][local];
    float q_ = bnq[wmq*2][local] + bnq[wmq*2+1][local];
    int bid = b*72 + st;
    bnpart[(size_t)bid*128 + tid] = s_;
    bnpart[(size_t)bid*128 + 64 + tid] = q_;
  }
}

// ---- combine BN partials: [576][128] -> [128] raw sums
__global__ __launch_bounds__(128) void bncombine_kernel(const float* __restrict__ bnpart, float* __restrict__ bnfin){
  int t = threadIdx.x;  // 128
  float a = 0.f;
  for (int blk = 0; blk < 576; ++blk) a += bnpart[(size_t)blk*128 + t];
  bnfin[t] = a;
}

// ---- BN apply + ReLU (in place on d_out), float4
__global__ __launch_bounds__(256) void bnapply_kernel(float* __restrict__ yb,
    const float* __restrict__ bnfin, const float* __restrict__ gamma, const float* __restrict__ beta){
  int gid = blockIdx.x*256 + threadIdx.x;  // exactly 1,179,648 float4s
  int o = (gid / 2304) & 63;
  float mean = bnfin[o] * (1.f/73728.f);
  float var = bnfin[64 + o] * (1.f/73728.f) - mean*mean;
  float inv = rsqrtf(var + 1e-5f);
  float g = gamma[o], be = beta[o];
  float4 v = ((const float4*)yb)[gid];
  v.x = fmaxf((v.x - mean)*inv*g + be, 0.f);
  v.y = fmaxf((v.y - mean)*inv*g + be, 0.f);
  v.z = fmaxf((v.z - mean)*inv*g + be, 0.f);
  v.w = fmaxf((v.w - mean)*inv*g + be, 0.f);
  ((float4*)yb)[gid] = v;
}

extern "C" void kernel_launch(void* const* d_in, const int* in_sizes, int n_in,
                              void* d_out, int out_size, void* d_ws, size_t ws_size,
                              hipStream_t stream) {
  const float* cen   = (const float*)d_in[0];
  const float* sumw  = (const float*)d_in[1];
  const float* qw    = (const float*)d_in[2];
  const float* kw    = (const float*)d_in[3];
  const float* vw    = (const float*)d_in[4];
  const float* ow    = (const float*)d_in[5];
  const float* gamma = (const float*)d_in[6];
  const float* beta  = (const float*)d_in[7];

  char* ws = (char*)d_ws;
  unsigned short* cenbf  = (unsigned short*)(ws + WS_CEN);
  unsigned short* cenbf1 = (unsigned short*)(ws + WS_CEN1);
  unsigned short* Wb     = (unsigned short*)(ws + WS_W);
  unsigned short* qbf    = (unsigned short*)(ws + WS_Q);
  unsigned short* KV     = (unsigned short*)(ws + WS_KV);
  float*          spart  = (float*)(ws + WS_SPART);
  float*          kkp    = (float*)(ws + WS_KKP);
  float*          qqp    = (float*)(ws + WS_QQP);
  float*          attnT  = (float*)(ws + WS_ATTN);
  unsigned short* Ab     = (unsigned short*)(ws + WS_AB);
  float*          bnp    = (float*)(ws + WS_BNP);
  float*          bnf    = (float*)(ws + WS_BNF);

  pad_kernel     <<<25088, 256, 0, stream>>>(cen, cenbf, cenbf1);
  prep_kernel    <<<2304, 256, 0, stream>>>(sumw, kw, vw, Wb);
  qproj_kernel   <<<dim3(36, 8), 256, 0, stream>>>(cen, qw, qbf);
  conv_kv_mfma   <<<dim3(36, 1, 32), 512, 0, stream>>>(cenbf, cenbf1, Wb, KV);
  scores_mfma    <<<dim3(18, 4, 8), 256, 0, stream>>>(KV, qbf, spart, kkp, qqp);
  softmax_kernel <<<32, 256, 0, stream>>>(spart, kkp, qqp, attnT);
  attnfold_kernel<<<1024, 256, 0, stream>>>(attnT, ow, Ab);
  ygemm_kernel   <<<dim3(72, 8), 256, 0, stream>>>(KV, Ab, (float*)d_out, bnp);
  bncombine_kernel<<<1, 128, 0, stream>>>(bnp, bnf);
  bnapply_kernel <<<4608, 256, 0, stream>>>((float*)d_out, bnf, gamma, beta);
}